// Round 18
// baseline (256.029 us; speedup 1.0000x reference)
//
#include <hip/hip_runtime.h>
#include <hip/hip_bf16.h>

namespace {

constexpr int B   = 1024;
constexpr int PEP = 15;
constexpr int MHCN = 44;
constexpr int S   = 59;    // sequence
constexpr int V   = 21;    // vocab / model dim
constexpr int C   = 3200;  // conv channels
constexpr int KW  = 9;     // depthwise kernel
constexpr int H   = 9;     // heads
constexpr int NH  = 800;
constexpr int SV  = S * V;   // 1239
constexpr int HD  = H * V;   // 189
constexpr int XF  = 1248;    // X2bf padded feature count (39*32)
constexpr float EPSF = 1e-5f;
constexpr float NLOG2E = -1.4426950408889634f;

typedef __attribute__((ext_vector_type(8))) short short8;   // 8 bf16 (4 VGPRs)
typedef __attribute__((ext_vector_type(4))) float f32x4;    // MFMA C/D frag
typedef __attribute__((ext_vector_type(2))) float f32x2;    // packed-f32 pair

__device__ __forceinline__ float sigm(float x) {
  return __builtin_amdgcn_rcpf(1.f + __expf(-x));
}
// single-instruction f32->bf16 (RNE) via cvt_pk; low 16 bits = cvt(src0)
__device__ __forceinline__ unsigned short f2bf(float f) {
  unsigned r;
  asm("v_cvt_pk_bf16_f32 %0, %1, %2" : "=v"(r) : "v"(f), "v"(f));
  return (unsigned short)r;
}
__device__ __forceinline__ unsigned pkbf(float a, float b) {
  unsigned r;
  asm("v_cvt_pk_bf16_f32 %0, %1, %2" : "=v"(r) : "v"(a), "v"(b));
  return r;  // a in low 16, b in high 16
}
__device__ __forceinline__ float bflo(unsigned d) {
  union { unsigned u; float f; } v; v.u = d << 16; return v.f;
}
__device__ __forceinline__ float bfhi(unsigned d) {
  union { unsigned u; float f; } v; v.u = d & 0xffff0000u; return v.f;
}

// ---------------- K0: pack all weights into MFMA B-fragment order (bf16) ----------------
// Frag convention (R8-verified): mfma(Afrag,Bfrag)=A@B^T with A[m=lr][k=lg*8+j],
// B[n=lr][k=lg*8+j], D[row=lg*4+reg][col=lr].  FB1 k=21 slot carries b1.
// g-rows (tt>=4) pre-scaled by -log2(e): sigm(g) = rcp(1+exp2(gs)).
__global__ void k_packW(const float* __restrict__ W1, const float* __restrict__ b1,
                        const float* __restrict__ Wd,
                        const float* __restrict__ bd, const float* __restrict__ g,
                        const float* __restrict__ bb, const float* __restrict__ m,
                        const float* __restrict__ vv, const float* __restrict__ W2,
                        const float* __restrict__ Wq, const float* __restrict__ Wk,
                        const float* __restrict__ Wv, const float* __restrict__ Wo,
                        const float* __restrict__ Wf1,
                        unsigned short* __restrict__ FB1, unsigned short* __restrict__ FB2,
                        unsigned short* __restrict__ FQKV, unsigned short* __restrict__ FWo,
                        unsigned short* __restrict__ FWf1, float* __restrict__ TAP) {
  int id = blockIdx.x * 256 + threadIdx.x;
  if (id < 400 * 64) {                       // FB1 (+bias at k==V); g-rows scaled
    int tau = id >> 6, l = id & 63;
    int ci = tau >> 3, tt = tau & 7;
    int lr = l & 15, lg = l >> 4;
    bool isg = (tt >= 4);
    int row = (!isg) ? (ci * 64 + tt * 16 + lr) : (C + ci * 64 + (tt - 4) * 16 + lr);
    float sc = isg ? NLOG2E : 1.f;
    for (int j = 0; j < 8; ++j) {
      int k = lg * 8 + j;
      float val = (k < V) ? W1[row * V + k] * sc : (k == V ? b1[row] * sc : 0.f);
      FB1[(size_t)tau * 512 + l * 8 + j] = f2bf(val);
    }
  } else if (id < 38400) {                   // FB2
    int id2 = id - 25600;
    int sg = id2 >> 6, l = id2 & 63;
    int ci = sg >> 2, rem = sg & 3, kt = rem >> 1, nt = rem & 1;
    int lr = l & 15, lg = l >> 4;
    int vc = nt * 16 + lr;
    for (int j = 0; j < 8; ++j) {
      int ch = ci * 64 + kt * 32 + lg * 8 + j;
      float val = (vc < V) ? W2[(size_t)vc * C + ch] : 0.f;
      FB2[(size_t)sg * 512 + l * 8 + j] = f2bf(val);
    }
  } else if (id < 41856) {                   // FQKV: 9h x 3mat x 2nt tiles
    int id2 = id - 38400;
    int tile = id2 >> 6, l = id2 & 63;
    int h = tile / 6, rem = tile - h * 6;
    int mat = rem >> 1, nt = rem & 1;
    int lr = l & 15, kg = l >> 4;
    int dcol = nt * 16 + lr;
    const float* W = (mat == 0) ? Wq : (mat == 1) ? Wk : Wv;
    const float scale = (mat == 0) ? 0.21821789023599236f : 1.f;  // 1/sqrt(21) into Q
    for (int j = 0; j < 8; ++j) {
      int u = kg * 8 + j;
      float val = (u < V && dcol < V) ? W[u * HD + h * V + dcol] * scale : 0.f;
      FQKV[(size_t)tile * 512 + l * 8 + j] = f2bf(val);
    }
  } else if (id < 43008) {                   // FWo: 9h x 2nt tiles, k = head-dim d
    int id2 = id - 41856;
    int tile = id2 >> 6, l = id2 & 63;
    int h = tile >> 1, nt = tile & 1;
    int lr = l & 15, kg = l >> 4;
    int vcol = nt * 16 + lr;
    for (int j = 0; j < 8; ++j) {
      int d = kg * 8 + j;
      float val = (d < V && vcol < V) ? Wo[(h * V + d) * V + vcol] : 0.f;
      FWo[(size_t)tile * 512 + l * 8 + j] = f2bf(val);
    }
  } else if (id < 46208) {                   // TAP
    int c = id - 43008;
    if (c < C) {
      float sc = g[c] * rsqrtf(vv[c] + EPSF);
      for (int k = 0; k < KW; ++k) TAP[c * 12 + k] = Wd[c * KW + k] * sc;
      TAP[c * 12 + 9]  = (bd[c] - m[c]) * sc + bb[c];
      TAP[c * 12 + 10] = 0.f;
      TAP[c * 12 + 11] = 0.f;
    }
  } else if (id < 46208 + 1950 * 64) {       // FWf1: 50 ntile x 39 kk tiles
    int id2 = id - 46208;
    int tile = id2 >> 6, l = id2 & 63;
    int ntg = tile / 39, kk = tile - ntg * 39;
    int lr = l & 15, kg = l >> 4;
    int n = ntg * 16 + lr;
    for (int j = 0; j < 8; ++j) {
      int f = kk * 32 + kg * 8 + j;
      float val = (f < SV) ? Wf1[(size_t)f * NH + n] : 0.f;
      FWf1[(size_t)tile * 512 + l * 8 + j] = f2bf(val);
    }
  }
}

// ---------------- K2: MFMA conv module, producer/consumer waves, 4-way split (R18) ----------------
// Grid 4B: block 4b+q handles chunk range [qoff[q], qoff[q]+qcnt[q]) (13/13/13/11,
// all odd so pipeline shape is uniform). 512 threads: waves 0-3 GLU producers,
// waves 4-7 conv consumers. Double-buffered glbuf, 1 barrier/chunk.
constexpr int GST = 74;  // glbuf row stride (bf16)
__constant__ const int QOFF[4] = {0, 13, 26, 39};
__constant__ const int QNP[4]  = {6, 6, 6, 5};   // pairs = (cnt-1)/2

__device__ __forceinline__ void glu_chunk(const unsigned short* fb1p, unsigned* glw0,
                                          short8 ax, int mt, int mypos) {
  f32x4 ga[4], gg[4];
#pragma unroll
  for (int tt = 0; tt < 4; ++tt) {
    short8 bf = *reinterpret_cast<const short8*>(fb1p + tt * 512);
    ga[tt] = __builtin_amdgcn_mfma_f32_16x16x32_bf16(ax, bf, (f32x4){0.f, 0.f, 0.f, 0.f}, 0, 0, 0);
  }
#pragma unroll
  for (int tt = 0; tt < 4; ++tt) {
    short8 bf = *reinterpret_cast<const short8*>(fb1p + (4 + tt) * 512);
    gg[tt] = __builtin_amdgcn_mfma_f32_16x16x32_bf16(ax, bf, (f32x4){0.f, 0.f, 0.f, 0.f}, 0, 0, 0);
  }
  if (mt < 3) {
#pragma unroll
    for (int tt = 0; tt < 4; ++tt) {
      unsigned* gw = glw0 + tt * (16 * GST / 2);
      float s0 = __builtin_amdgcn_rcpf(1.f + __builtin_amdgcn_exp2f(gg[tt][0]));
      float s1 = __builtin_amdgcn_rcpf(1.f + __builtin_amdgcn_exp2f(gg[tt][1]));
      float s2 = __builtin_amdgcn_rcpf(1.f + __builtin_amdgcn_exp2f(gg[tt][2]));
      float s3 = __builtin_amdgcn_rcpf(1.f + __builtin_amdgcn_exp2f(gg[tt][3]));
      gw[0] = pkbf(ga[tt][0] * s0, ga[tt][1] * s1);
      gw[1] = pkbf(ga[tt][2] * s2, ga[tt][3] * s3);
    }
  } else {
#pragma unroll
    for (int tt = 0; tt < 4; ++tt) {
      unsigned* gw = glw0 + tt * (16 * GST / 2);
      float g0 = (mypos + 0 < S) ? ga[tt][0] * __builtin_amdgcn_rcpf(1.f + __builtin_amdgcn_exp2f(gg[tt][0])) : 0.f;
      float g1 = (mypos + 1 < S) ? ga[tt][1] * __builtin_amdgcn_rcpf(1.f + __builtin_amdgcn_exp2f(gg[tt][1])) : 0.f;
      float g2 = (mypos + 2 < S) ? ga[tt][2] * __builtin_amdgcn_rcpf(1.f + __builtin_amdgcn_exp2f(gg[tt][2])) : 0.f;
      float g3 = (mypos + 3 < S) ? ga[tt][3] * __builtin_amdgcn_rcpf(1.f + __builtin_amdgcn_exp2f(gg[tt][3])) : 0.f;
      gw[0] = pkbf(g0, g1);
      gw[1] = pkbf(g2, g3);
    }
  }
}

__device__ __forceinline__ void conv_chunk(const unsigned* glr, const float* tapp,
                                           const unsigned short* fb2p,
                                           unsigned short* sbw, const unsigned short* sbr,
                                           int mt, f32x4 (&acc2)[2]) {
  const float4 t0 = *reinterpret_cast<const float4*>(tapp);
  const float4 t1 = *reinterpret_cast<const float4*>(tapp + 4);
  const float4 t2 = *reinterpret_cast<const float4*>(tapp + 8);
  const float tap[9] = {t0.x, t0.y, t0.z, t0.w, t1.x, t1.y, t1.z, t1.w, t2.x};
  const float sh = t2.y;
  float gv[24];
#pragma unroll
  for (int i2 = 0; i2 < 12; ++i2) {
    const unsigned d = glr[i2];
    gv[2 * i2]     = bflo(d);
    gv[2 * i2 + 1] = bfhi(d);
  }
  f32x2 q[16];
#pragma unroll
  for (int j = 0; j < 16; ++j) q[j] = (f32x2){gv[j], gv[j + 8]};
#pragma unroll
  for (int i2 = 0; i2 < 8; ++i2) {
    f32x2 ac = (f32x2){sh, sh};
#pragma unroll
    for (int k = 0; k < KW; ++k) {
      f32x2 tk = (f32x2){tap[k], tap[k]};
      ac = ac + q[i2 + k] * tk;   // elementwise; contracts to (pk_)fma
    }
    const float a0 = ac.x, a1 = ac.y;
    const float s0 = a0 * __builtin_amdgcn_rcpf(1.f + __builtin_amdgcn_exp2f(a0 * NLOG2E));
    const float s1 = a1 * __builtin_amdgcn_rcpf(1.f + __builtin_amdgcn_exp2f(a1 * NLOG2E));
    sbw[i2 * 72] = f2bf(s0);
    unsigned short hv = f2bf(s1);
    if (mt == 3 && i2 >= 3) hv = 0;   // pos >= 59 masked
    sbw[(i2 + 8) * 72] = hv;
  }
#pragma unroll
  for (int kt = 0; kt < 2; ++kt) {
    short8 a2f = *reinterpret_cast<const short8*>(sbr + kt * 32);
#pragma unroll
    for (int nt = 0; nt < 2; ++nt) {
      short8 b2f = *reinterpret_cast<const short8*>(fb2p + (kt * 2 + nt) * 512);
      acc2[nt] = __builtin_amdgcn_mfma_f32_16x16x32_bf16(a2f, b2f, acc2[nt], 0, 0, 0);
    }
  }
}

__global__ __launch_bounds__(512) void k_conv(
    const float* __restrict__ pep, const float* __restrict__ mhc,
    const unsigned short* __restrict__ FB1, const unsigned short* __restrict__ FB2,
    const float* __restrict__ TAP, float* __restrict__ Yp) {
  __shared__ __align__(16) unsigned char smem[2 * 64 * GST * 2 + 4 * 16 * 72 * 2];  // 28160 B
  unsigned short* Xbf = reinterpret_cast<unsigned short*>(smem);   // [64][40] setup overlay
  unsigned short* glA = reinterpret_cast<unsigned short*>(smem);   // [64][GST]
  unsigned short* glB = glA + 64 * GST;                            // [64][GST]
  unsigned short* Sb  = glB + 64 * GST;                            // [4][16*72]
  const int t = threadIdx.x;
  const int b = blockIdx.x >> 2;
  const int q = blockIdx.x & 3;
  const int lane = t & 63;
  const int w = t >> 6;          // 0-3 GLU producers, 4-7 conv consumers
  const int lr = lane & 15;
  const int lg = lane >> 4;
  const bool isGlu = (w < 4);
  const int mt = isGlu ? w : (w - 4);   // M-tile this wave owns
  const int mypos = mt * 16 + lg * 4;
  const int qoff = QOFF[q];
  const int npairs = QNP[q];

  // ---- phase A: X -> bf16 (first 256 threads; rows>=59/cols>=21 zero; col21=1.0) ----
  if (t < 256) {
    const int row = t >> 2, qq = t & 3;
    const float* xr = (row < PEP) ? pep + ((size_t)b * PEP + row) * V
                    : (row < S)   ? mhc + ((size_t)b * MHCN + (row - PEP)) * V
                                  : nullptr;
#pragma unroll
    for (int i2 = 0; i2 < 5; ++i2) {
      int c0 = qq * 10 + 2 * i2;
      float f0 = (xr && c0 < V) ? xr[c0] : 0.f;
      float f1 = (xr && c0 + 1 < V) ? xr[c0 + 1] : ((xr && c0 + 1 == V) ? 1.f : 0.f);
      *reinterpret_cast<unsigned*>(&Xbf[row * 40 + c0]) = pkbf(f0, f1);
    }
  }
  __syncthreads();

  short8 ax = {};
  if (isGlu) ax = *reinterpret_cast<const short8*>(&Xbf[(mt * 16 + lr) * 40 + lg * 8]);
  __syncthreads();  // Xbf dead; glA may now be overwritten

  // ---- zero left halos of BOTH buffers (first 256 threads: 64 rows x 2 dw x 2 buf) ----
  if (t < 256) {
    unsigned short* buf = (t < 128) ? glA : glB;
    const int i2 = t & 127;
    *reinterpret_cast<unsigned*>(&buf[(i2 >> 1) * GST + (i2 & 1) * 2]) = 0u;
  }

  f32x4 acc2[2];
  acc2[0] = (f32x4){0.f, 0.f, 0.f, 0.f};
  acc2[1] = (f32x4){0.f, 0.f, 0.f, 0.f};

  // loop-invariant addresses (offset by this block's chunk range)
  unsigned* glwA = reinterpret_cast<unsigned*>(&glA[lr * GST + 4 + mypos]);
  unsigned* glwB = reinterpret_cast<unsigned*>(&glB[lr * GST + 4 + mypos]);
  const unsigned* glrA = reinterpret_cast<const unsigned*>(&glA[lane * GST + mt * 16]);
  const unsigned* glrB = reinterpret_cast<const unsigned*>(&glB[lane * GST + mt * 16]);
  unsigned short* sbw = Sb + mt * (16 * 72) + lane;
  const unsigned short* sbr = Sb + mt * (16 * 72) + lr * 72 + lg * 8;
  const unsigned short* fb1p = FB1 + (size_t)qoff * 8 * 512 + lane * 8;
  const unsigned short* fb2p = FB2 + (size_t)qoff * 4 * 512 + lane * 8;
  const float* tapp = TAP + ((size_t)qoff * 64 + lane) * 12;

  // ---- prologue: GLU(chunk 0) -> A ----
  if (isGlu) glu_chunk(fb1p, glwA, ax, mt, mypos);
  __syncthreads();

  // ---- pipelined pair loop: 1 barrier per chunk; producers fill, consumers drain ----
  for (int p = 0; p < npairs; ++p) {
    if (isGlu) glu_chunk(fb1p + 4096, glwB, ax, mt, mypos);            // fill B = 2p+1
    else       conv_chunk(glrA, tapp, fb2p, sbw, sbr, mt, acc2);       // consume A = 2p
    __syncthreads();
    if (isGlu) glu_chunk(fb1p + 2 * 4096, glwA, ax, mt, mypos);        // fill A = 2p+2
    else       conv_chunk(glrB, tapp + 768, fb2p + 2048, sbw, sbr, mt, acc2);  // B = 2p+1
    __syncthreads();
    fb1p += 2 * 4096;
    fb2p += 2 * 2048;
    tapp += 2 * 768;
  }
  // ---- epilogue: consume A = last chunk (odd count; filled in final pair iter) ----
  if (!isGlu) {
    conv_chunk(glrA, tapp, fb2p, sbw, sbr, mt, acc2);
    // ---- write partial down-proj to global (plain stores, deterministic) ----
    float* yp = Yp + (size_t)blockIdx.x * SV;
#pragma unroll
    for (int nt = 0; nt < 2; ++nt) {
#pragma unroll
      for (int r = 0; r < 4; ++r) {
        const int pos = mypos + r, vc = nt * 16 + lr;
        if (pos < S && vc < V) yp[pos * V + vc] = acc2[nt][r];
      }
    }
  }
}

// ---------------- K3: fused LN + MFMA attention + Wo + residual + LN -> X2bf ----------------
// Prologue absorbs k_ln: X1f = LN(residual + sum of 4 Yp partials + b2).
__global__ __launch_bounds__(256) void k_attn(
    const float* __restrict__ pep, const float* __restrict__ mhc,
    const float* __restrict__ Yp, const float* __restrict__ b2,
    const unsigned short* __restrict__ FQKV,
    const unsigned short* __restrict__ FWo, const float* __restrict__ lng,
    const float* __restrict__ lnb, unsigned short* __restrict__ X2bf) {
  __shared__ float X1f[64 * 21];
  __shared__ __align__(16) unsigned short Qb[64 * 40];
  __shared__ __align__(16) unsigned short Kb[64 * 40];
  __shared__ __align__(16) unsigned short Vt[32 * 72];
  __shared__ __align__(16) unsigned short Pt[64 * 72];
  __shared__ __align__(16) unsigned short Oh[64 * 40];
  const int t = threadIdx.x;
  const int b = blockIdx.x;
  const int lane = t & 63;
  const int w = t >> 6;
  const int lr = lane & 15;
  const int lg = lane >> 4;
  const int mypos = w * 16 + lg * 4;

  // ---- prologue: conv-module LN (was k_ln) -> X1f ----
  if (t < 64) {
    if (t < S) {
      const float* xr = (t < PEP) ? pep + ((size_t)b * PEP + t) * V
                                  : mhc + ((size_t)b * MHCN + (t - PEP)) * V;
      const float* y0 = Yp + (size_t)(4 * b) * SV + t * V;
      float z[V];
      float mn = 0.f;
#pragma unroll
      for (int v = 0; v < V; ++v) {
        z[v] = xr[v] + ((y0[v] + y0[SV + v]) + (y0[2 * SV + v] + y0[3 * SV + v])) + b2[v];
        mn += z[v];
      }
      mn *= (1.f / V);
      float var = 0.f;
#pragma unroll
      for (int v = 0; v < V; ++v) {
        float d = z[v] - mn;
        var = fmaf(d, d, var);
      }
      const float inv = rsqrtf(var * (1.f / V) + EPSF);
#pragma unroll
      for (int v = 0; v < V; ++v)
        X1f[t * 21 + v] = (z[v] - mn) * inv * lng[v] + lnb[v];
    } else {
#pragma unroll
      for (int v = 0; v < V; ++v) X1f[t * 21 + v] = 0.f;
    }
  }
  __syncthreads();

  short8 ax;
  {
    const int rowi = w * 16 + lr;
#pragma unroll
    for (int j = 0; j < 8; ++j) {
      int col = lg * 8 + j;
      ax[j] = (short)((col < V) ? f2bf(X1f[rowi * 21 + col]) : (unsigned short)0);
    }
  }
  f32x4 accw[2];
  accw[0] = (f32x4){0.f, 0.f, 0.f, 0.f};
  accw[1] = (f32x4){0.f, 0.f, 0.f, 0.f};

  for (int h = 0; h < H; ++h) {
    const unsigned short* fq = FQKV + (size_t)(h * 6) * 512;
    f32x4 dq[2], dk[2], dv[2];
#pragma unroll
    for (int nt = 0; nt < 2; ++nt) {
      short8 bq = *reinterpret_cast<const short8*>(fq + (0 + nt) * 512 + lane * 8);
      dq[nt] = __builtin_amdgcn_mfma_f32_16x16x32_bf16(ax, bq, (f32x4){0.f, 0.f, 0.f, 0.f}, 0, 0, 0);
      short8 bk = *reinterpret_cast<const short8*>(fq + (2 + nt) * 512 + lane * 8);
      dk[nt] = __builtin_amdgcn_mfma_f32_16x16x32_bf16(ax, bk, (f32x4){0.f, 0.f, 0.f, 0.f}, 0, 0, 0);
      short8 bv = *reinterpret_cast<const short8*>(fq + (4 + nt) * 512 + lane * 8);
      dv[nt] = __builtin_amdgcn_mfma_f32_16x16x32_bf16(ax, bv, (f32x4){0.f, 0.f, 0.f, 0.f}, 0, 0, 0);
    }
#pragma unroll
    for (int nt = 0; nt < 2; ++nt) {
      const int d = nt * 16 + lr;
#pragma unroll
      for (int r = 0; r < 4; ++r) {
        const int pos = mypos + r;
        Qb[pos * 40 + d] = f2bf(dq[nt][r]);
        Kb[pos * 40 + d] = f2bf(dk[nt][r]);
      }
      // Vt row d: positions mypos..mypos+3 contiguous -> 2 packed dwords
      *reinterpret_cast<unsigned*>(&Vt[d * 72 + mypos])     = pkbf(dv[nt][0], dv[nt][1]);
      *reinterpret_cast<unsigned*>(&Vt[d * 72 + mypos + 2]) = pkbf(dv[nt][2], dv[nt][3]);
    }
    __syncthreads();  // bar1: Qb/Kb/Vt complete

    short8 bqf = *reinterpret_cast<const short8*>(&Qb[(w * 16 + lr) * 40 + lg * 8]);
    f32x4 st[4];
#pragma unroll
    for (int mt = 0; mt < 4; ++mt) {
      short8 akf = *reinterpret_cast<const short8*>(&Kb[(mt * 16 + lr) * 40 + lg * 8]);
      st[mt] = __builtin_amdgcn_mfma_f32_16x16x32_bf16(akf, bqf, (f32x4){0.f, 0.f, 0.f, 0.f}, 0, 0, 0);
    }
    float mx = -1e30f;
#pragma unroll
    for (int mt = 0; mt < 4; ++mt)
#pragma unroll
      for (int r = 0; r < 4; ++r) {
        const int j = mt * 16 + lg * 4 + r;
        float sv = (j < S) ? st[mt][r] : -1e30f;
        st[mt][r] = sv;
        mx = fmaxf(mx, sv);
      }
    mx = fmaxf(mx, __shfl_xor(mx, 16));
    mx = fmaxf(mx, __shfl_xor(mx, 32));
    float sum = 0.f;
#pragma unroll
    for (int mt = 0; mt < 4; ++mt)
#pragma unroll
      for (int r = 0; r < 4; ++r) {
        float e = __expf(st[mt][r] - mx);
        st[mt][r] = e;
        sum += e;
      }
    sum += __shfl_xor(sum, 16);
    sum += __shfl_xor(sum, 32);
#pragma unroll
    for (int mt = 0; mt < 4; ++mt) {
#pragma unroll
      for (int s2 = 0; s2 < 2; ++s2) {
        *reinterpret_cast<unsigned*>(&Pt[(w * 16 + lr) * 72 + mt * 16 + lg * 4 + 2 * s2]) =
            pkbf(st[mt][2 * s2], st[mt][2 * s2 + 1]);
      }
    }
    short8 bp0 = *reinterpret_cast<const short8*>(&Pt[(w * 16 + lr) * 72 + lg * 8]);
    short8 bp1 = *reinterpret_cast<const short8*>(&Pt[(w * 16 + lr) * 72 + 32 + lg * 8]);
    f32x4 ot[2];
    ot[0] = (f32x4){0.f, 0.f, 0.f, 0.f};
    ot[1] = (f32x4){0.f, 0.f, 0.f, 0.f};
#pragma unroll
    for (int mt = 0; mt < 2; ++mt) {
      short8 av0 = *reinterpret_cast<const short8*>(&Vt[(mt * 16 + lr) * 72 + lg * 8]);
      ot[mt] = __builtin_amdgcn_mfma_f32_16x16x32_bf16(av0, bp0, ot[mt], 0, 0, 0);
      short8 av1 = *reinterpret_cast<const short8*>(&Vt[(mt * 16 + lr) * 72 + 32 + lg * 8]);
      ot[mt] = __builtin_amdgcn_mfma_f32_16x16x32_bf16(av1, bp1, ot[mt], 0, 0, 0);
    }
    const float inv = __builtin_amdgcn_rcpf(sum);
#pragma unroll
    for (int mt = 0; mt < 2; ++mt) {
#pragma unroll
      for (int s2 = 0; s2 < 2; ++s2) {
        *reinterpret_cast<unsigned*>(&Oh[(w * 16 + lr) * 40 + mt * 16 + lg * 4 + 2 * s2]) =
            pkbf(ot[mt][2 * s2] * inv, ot[mt][2 * s2 + 1] * inv);
      }
    }
    short8 ao = *reinterpret_cast<const short8*>(&Oh[(w * 16 + lr) * 40 + lg * 8]);
#pragma unroll
    for (int nt = 0; nt < 2; ++nt) {
      short8 bw = *reinterpret_cast<const short8*>(FWo + (size_t)(h * 2 + nt) * 512 + lane * 8);
      accw[nt] = __builtin_amdgcn_mfma_f32_16x16x32_bf16(ao, bw, accw[nt], 0, 0, 0);
    }
    __syncthreads();  // bar2
  }

  // ---- epilogue: residual + LayerNorm -> X2bf (bf16, padded to XF) ----
#pragma unroll
  for (int r = 0; r < 4; ++r) {
    const int pos = mypos + r;
    const bool v1ok = (lr < 5);
    const float x0 = (pos < S) ? X1f[pos * 21 + lr] : 0.f;
    const float x1 = (v1ok && pos < S) ? X1f[pos * 21 + 16 + lr] : 0.f;
    float z0 = accw[0][r] + x0;
    float z1 = v1ok ? (accw[1][r] + x1) : 0.f;
    float s = z0 + z1;
    s += __shfl_xor(s, 1); s += __shfl_xor(s, 2);
    s += __shfl_xor(s, 4); s += __shfl_xor(s, 8);
    const float mn = s * (1.f / V);
    const float d0 = z0 - mn;
    const float d1 = v1ok ? (z1 - mn) : 0.f;
    float vq = d0 * d0 + d1 * d1;
    vq += __shfl_xor(vq, 1); vq += __shfl_xor(vq, 2);
    vq += __shfl_xor(vq, 4); vq += __shfl_xor(vq, 8);
    const float inv = rsqrtf(vq * (1.f / V) + EPSF);
    if (pos < S) {
      X2bf[(size_t)b * XF + pos * 21 + lr] = f2bf(d0 * inv * lng[lr] + lnb[lr]);
      if (v1ok)
        X2bf[(size_t)b * XF + pos * 21 + 16 + lr] = f2bf(d1 * inv * lng[16 + lr] + lnb[16 + lr]);
    }
  }
  if (t < XF - SV) X2bf[(size_t)b * XF + SV + t] = 0;  // zero K-pad
}

// ---------------- K5: MFMA head GEMM [1024,1248bf]@[1248,800] + silu + BN -> Hb ----------------
// grid (16,10): block = 64 rows x 80 cols; wave = 16-row strip x 5 N-tiles.
__global__ __launch_bounds__(256) void k_f1(
    const unsigned short* __restrict__ X2bf, const unsigned short* __restrict__ FWf1,
    const float* __restrict__ bf1, const float* __restrict__ g2,
    const float* __restrict__ bb2, const float* __restrict__ m2,
    const float* __restrict__ v2, float* __restrict__ Hb) {
  const int t = threadIdx.x;
  const int lane = t & 63;
  const int w = t >> 6;
  const int lr = lane & 15;
  const int lg = lane >> 4;
  const int Mb = blockIdx.x * 64;
  const int NbT = blockIdx.y * 5;  // N-tile base (80 cols)

  const unsigned short* ap = X2bf + (size_t)(Mb + w * 16 + lr) * XF + lg * 8;
  const unsigned short* bp = FWf1 + (size_t)NbT * 39 * 512 + lane * 8;
  f32x4 acc[5];
#pragma unroll
  for (int nt = 0; nt < 5; ++nt) acc[nt] = (f32x4){0.f, 0.f, 0.f, 0.f};

  for (int kk = 0; kk < 39; ++kk) {
    short8 af = *reinterpret_cast<const short8*>(ap + kk * 32);
#pragma unroll
    for (int nt = 0; nt < 5; ++nt) {
      short8 bf = *reinterpret_cast<const short8*>(bp + ((size_t)nt * 39 + kk) * 512);
      acc[nt] = __builtin_amdgcn_mfma_f32_16x16x32_bf16(af, bf, acc[nt], 0, 0, 0);
    }
  }
#pragma unroll
  for (int nt = 0; nt < 5; ++nt) {
    const int n = (NbT + nt) * 16 + lr;
    const float sc = g2[n] * rsqrtf(v2[n] + EPSF);
    const float sh = bb2[n] - m2[n] * sc;
    const float bias = bf1[n];
#pragma unroll
    for (int r = 0; r < 4; ++r) {
      const int row = Mb + w * 16 + lg * 4 + r;
      float hh = acc[nt][r] + bias;
      hh = fmaf(hh * sigm(hh), sc, sh);
      Hb[(size_t)row * NH + n] = hh;
    }
  }
}

// ---------------- K6: relu(Hb@Wf2+bf2) @ Wf3 + bf3 -> out [B,2] ----------------
__global__ __launch_bounds__(64) void k_f23(
    const float* __restrict__ Hb, const float* __restrict__ Wf2, const float* __restrict__ bf2,
    const float* __restrict__ Wf3, const float* __restrict__ bf3, float* __restrict__ out) {
  __shared__ __align__(16) float hs[NH];
  const int t = threadIdx.x;
  const int b = blockIdx.x;
  for (int i = t; i < NH; i += 64) hs[i] = Hb[(size_t)b * NH + i];
  __syncthreads();
  float acc = bf2[t];
  for (int n = 0; n < NH; n += 4) {
    const float4 hv = *reinterpret_cast<const float4*>(&hs[n]);
    acc = fmaf(hv.x, Wf2[n * 64 + t], acc);
    acc = fmaf(hv.y, Wf2[(n + 1) * 64 + t], acc);
    acc = fmaf(hv.z, Wf2[(n + 2) * 64 + t], acc);
    acc = fmaf(hv.w, Wf2[(n + 3) * 64 + t], acc);
  }
  const float mid = fmaxf(acc, 0.f);
  float p0 = mid * Wf3[t * 2 + 0];
  float p1 = mid * Wf3[t * 2 + 1];
#pragma unroll
  for (int off = 32; off > 0; off >>= 1) {
    p0 += __shfl_down(p0, off);
    p1 += __shfl_down(p1, off);
  }
  if (t == 0) {
    out[b * 2 + 0] = p0 + bf3[0];
    out[b * 2 + 1] = p1 + bf3[1];
  }
}

}  // namespace

extern "C" void kernel_launch(void* const* d_in, const int* in_sizes, int n_in,
                              void* d_out, int out_size, void* d_ws, size_t ws_size,
                              hipStream_t stream) {
  const float* pep   = (const float*)d_in[0];
  const float* mhc   = (const float*)d_in[1];
  const float* W1    = (const float*)d_in[2];
  const float* b1    = (const float*)d_in[3];
  const float* Wd    = (const float*)d_in[4];
  const float* bd    = (const float*)d_in[5];
  const float* bn1_g = (const float*)d_in[6];
  const float* bn1_b = (const float*)d_in[7];
  const float* bn1_m = (const float*)d_in[8];
  const float* bn1_v = (const float*)d_in[9];
  const float* W2    = (const float*)d_in[10];
  const float* b2    = (const float*)d_in[11];
  const float* ln_g  = (const float*)d_in[12];
  const float* ln_b  = (const float*)d_in[13];
  const float* Wq    = (const float*)d_in[14];
  const float* Wk    = (const float*)d_in[15];
  const float* Wv    = (const float*)d_in[16];
  const float* Wo    = (const float*)d_in[17];
  const float* Wf1   = (const float*)d_in[18];
  const float* bf1   = (const float*)d_in[19];
  const float* bn2_g = (const float*)d_in[20];
  const float* bn2_b = (const float*)d_in[21];
  const float* bn2_m = (const float*)d_in[22];
  const float* bn2_v = (const float*)d_in[23];
  const float* Wf2   = (const float*)d_in[24];
  const float* bf2   = (const float*)d_in[25];
  const float* Wf3   = (const float*)d_in[26];
  const float* bf3   = (const float*)d_in[27];
  float* out = (float*)d_out;

  float* ws = (float*)d_ws;
  unsigned short* X2bf = (unsigned short*)ws;                // [B,XF] bf16
  float* Hb = (float*)(X2bf + (size_t)B * XF);               // [B,NH] f32
  float* TAP = Hb + (size_t)B * NH;                          // [C,12]
  unsigned short* FB1  = (unsigned short*)(TAP + (size_t)C * 12);
  unsigned short* FB2  = FB1 + (size_t)400 * 512;
  unsigned short* FQKV = FB2 + (size_t)200 * 512;
  unsigned short* FWo  = FQKV + (size_t)54 * 512;
  unsigned short* FWf1 = FWo + (size_t)18 * 512;             // 1950 x 512 bf16
  float* Yp = (float*)(FWf1 + (size_t)1950 * 512);           // [4B][SV]

  k_packW<<<669, 256, 0, stream>>>(W1, b1, Wd, bd, bn1_g, bn1_b, bn1_m, bn1_v, W2,
                                   Wq, Wk, Wv, Wo, Wf1, FB1, FB2, FQKV, FWo, FWf1, TAP);
  k_conv<<<4 * B, 512, 0, stream>>>(pep, mhc, FB1, FB2, TAP, Yp);
  k_attn<<<B, 256, 0, stream>>>(pep, mhc, Yp, b2, FQKV, FWo, ln_g, ln_b, X2bf);
  dim3 g5(16, 10);
  k_f1<<<g5, 256, 0, stream>>>(X2bf, FWf1, bf1, bn2_g, bn2_b, bn2_m, bn2_v, Hb);
  k_f23<<<B, 64, 0, stream>>>(Hb, Wf2, bf2, Wf3, bf3, out);
}

// Round 19
// 241.530 us; speedup vs baseline: 1.0600x; 1.0600x over previous
//
#include <hip/hip_runtime.h>
#include <hip/hip_bf16.h>

namespace {

constexpr int B   = 1024;
constexpr int PEP = 15;
constexpr int MHCN = 44;
constexpr int S   = 59;    // sequence
constexpr int V   = 21;    // vocab / model dim
constexpr int C   = 3200;  // conv channels
constexpr int KW  = 9;     // depthwise kernel
constexpr int H   = 9;     // heads
constexpr int NH  = 800;
constexpr int SV  = S * V;   // 1239
constexpr int HD  = H * V;   // 189
constexpr int XF  = 1248;    // X2bf padded feature count (39*32)
constexpr float EPSF = 1e-5f;
constexpr int CHALF = 25;    // conv chunks per half-block
constexpr float NLOG2E = -1.4426950408889634f;

typedef __attribute__((ext_vector_type(8))) short short8;   // 8 bf16 (4 VGPRs)
typedef __attribute__((ext_vector_type(4))) float f32x4;    // MFMA C/D frag
typedef __attribute__((ext_vector_type(2))) float f32x2;    // packed-f32 pair

__device__ __forceinline__ float sigm(float x) {
  return __builtin_amdgcn_rcpf(1.f + __expf(-x));
}
// single-instruction f32->bf16 (RNE) via cvt_pk; low 16 bits = cvt(src0)
__device__ __forceinline__ unsigned short f2bf(float f) {
  unsigned r;
  asm("v_cvt_pk_bf16_f32 %0, %1, %2" : "=v"(r) : "v"(f), "v"(f));
  return (unsigned short)r;
}
__device__ __forceinline__ unsigned pkbf(float a, float b) {
  unsigned r;
  asm("v_cvt_pk_bf16_f32 %0, %1, %2" : "=v"(r) : "v"(a), "v"(b));
  return r;  // a in low 16, b in high 16
}
__device__ __forceinline__ float bflo(unsigned d) {
  union { unsigned u; float f; } v; v.u = d << 16; return v.f;
}
__device__ __forceinline__ float bfhi(unsigned d) {
  union { unsigned u; float f; } v; v.u = d & 0xffff0000u; return v.f;
}

// ---------------- K0: pack all weights into MFMA B-fragment order (bf16) ----------------
// Frag convention (R8-verified): mfma(Afrag,Bfrag)=A@B^T with A[m=lr][k=lg*8+j],
// B[n=lr][k=lg*8+j], D[row=lg*4+reg][col=lr].  FB1 k=21 slot carries b1.
// g-rows (tt>=4) pre-scaled by -log2(e): sigm(g) = rcp(1+exp2(gs)).
__global__ void k_packW(const float* __restrict__ W1, const float* __restrict__ b1,
                        const float* __restrict__ Wd,
                        const float* __restrict__ bd, const float* __restrict__ g,
                        const float* __restrict__ bb, const float* __restrict__ m,
                        const float* __restrict__ vv, const float* __restrict__ W2,
                        const float* __restrict__ Wq, const float* __restrict__ Wk,
                        const float* __restrict__ Wv, const float* __restrict__ Wo,
                        const float* __restrict__ Wf1,
                        unsigned short* __restrict__ FB1, unsigned short* __restrict__ FB2,
                        unsigned short* __restrict__ FQKV, unsigned short* __restrict__ FWo,
                        unsigned short* __restrict__ FWf1, float* __restrict__ TAP) {
  int id = blockIdx.x * 256 + threadIdx.x;
  if (id < 400 * 64) {                       // FB1 (+bias at k==V); g-rows scaled
    int tau = id >> 6, l = id & 63;
    int ci = tau >> 3, tt = tau & 7;
    int lr = l & 15, lg = l >> 4;
    bool isg = (tt >= 4);
    int row = (!isg) ? (ci * 64 + tt * 16 + lr) : (C + ci * 64 + (tt - 4) * 16 + lr);
    float sc = isg ? NLOG2E : 1.f;
    for (int j = 0; j < 8; ++j) {
      int k = lg * 8 + j;
      float val = (k < V) ? W1[row * V + k] * sc : (k == V ? b1[row] * sc : 0.f);
      FB1[(size_t)tau * 512 + l * 8 + j] = f2bf(val);
    }
  } else if (id < 38400) {                   // FB2
    int id2 = id - 25600;
    int sg = id2 >> 6, l = id2 & 63;
    int ci = sg >> 2, rem = sg & 3, kt = rem >> 1, nt = rem & 1;
    int lr = l & 15, lg = l >> 4;
    int vc = nt * 16 + lr;
    for (int j = 0; j < 8; ++j) {
      int ch = ci * 64 + kt * 32 + lg * 8 + j;
      float val = (vc < V) ? W2[(size_t)vc * C + ch] : 0.f;
      FB2[(size_t)sg * 512 + l * 8 + j] = f2bf(val);
    }
  } else if (id < 41856) {                   // FQKV: 9h x 3mat x 2nt tiles
    int id2 = id - 38400;
    int tile = id2 >> 6, l = id2 & 63;
    int h = tile / 6, rem = tile - h * 6;
    int mat = rem >> 1, nt = rem & 1;
    int lr = l & 15, kg = l >> 4;
    int dcol = nt * 16 + lr;
    const float* W = (mat == 0) ? Wq : (mat == 1) ? Wk : Wv;
    const float scale = (mat == 0) ? 0.21821789023599236f : 1.f;  // 1/sqrt(21) into Q
    for (int j = 0; j < 8; ++j) {
      int u = kg * 8 + j;
      float val = (u < V && dcol < V) ? W[u * HD + h * V + dcol] * scale : 0.f;
      FQKV[(size_t)tile * 512 + l * 8 + j] = f2bf(val);
    }
  } else if (id < 43008) {                   // FWo: 9h x 2nt tiles, k = head-dim d
    int id2 = id - 41856;
    int tile = id2 >> 6, l = id2 & 63;
    int h = tile >> 1, nt = tile & 1;
    int lr = l & 15, kg = l >> 4;
    int vcol = nt * 16 + lr;
    for (int j = 0; j < 8; ++j) {
      int d = kg * 8 + j;
      float val = (d < V && vcol < V) ? Wo[(h * V + d) * V + vcol] : 0.f;
      FWo[(size_t)tile * 512 + l * 8 + j] = f2bf(val);
    }
  } else if (id < 46208) {                   // TAP
    int c = id - 43008;
    if (c < C) {
      float sc = g[c] * rsqrtf(vv[c] + EPSF);
      for (int k = 0; k < KW; ++k) TAP[c * 12 + k] = Wd[c * KW + k] * sc;
      TAP[c * 12 + 9]  = (bd[c] - m[c]) * sc + bb[c];
      TAP[c * 12 + 10] = 0.f;
      TAP[c * 12 + 11] = 0.f;
    }
  } else if (id < 46208 + 1950 * 64) {       // FWf1: 50 ntile x 39 kk tiles
    int id2 = id - 46208;
    int tile = id2 >> 6, l = id2 & 63;
    int ntg = tile / 39, kk = tile - ntg * 39;
    int lr = l & 15, kg = l >> 4;
    int n = ntg * 16 + lr;
    for (int j = 0; j < 8; ++j) {
      int f = kk * 32 + kg * 8 + j;
      float val = (f < SV) ? Wf1[(size_t)f * NH + n] : 0.f;
      FWf1[(size_t)tile * 512 + l * 8 + j] = f2bf(val);
    }
  }
}

// ---------------- K2: MFMA conv module, producer/consumer waves (R19) ----------------
// 2-way split (R18's 4-way regressed: per-block fixed costs outweighed packing).
// 512 threads: waves 0-3 GLU producers, waves 4-7 conv consumers; double-buffered
// glbuf, 1 barrier/chunk. R19 fix: tap-pair broadcasts hoisted out of the inner
// loop (R15 regression: tk built inside the 8x9 loop = ~144 redundant movs/chunk).
constexpr int GST = 74;  // glbuf row stride (bf16)

__device__ __forceinline__ void glu_chunk(const unsigned short* fb1p, unsigned* glw0,
                                          short8 ax, int mt, int mypos) {
  f32x4 ga[4], gg[4];
#pragma unroll
  for (int tt = 0; tt < 4; ++tt) {
    short8 bf = *reinterpret_cast<const short8*>(fb1p + tt * 512);
    ga[tt] = __builtin_amdgcn_mfma_f32_16x16x32_bf16(ax, bf, (f32x4){0.f, 0.f, 0.f, 0.f}, 0, 0, 0);
  }
#pragma unroll
  for (int tt = 0; tt < 4; ++tt) {
    short8 bf = *reinterpret_cast<const short8*>(fb1p + (4 + tt) * 512);
    gg[tt] = __builtin_amdgcn_mfma_f32_16x16x32_bf16(ax, bf, (f32x4){0.f, 0.f, 0.f, 0.f}, 0, 0, 0);
  }
  if (mt < 3) {
#pragma unroll
    for (int tt = 0; tt < 4; ++tt) {
      unsigned* gw = glw0 + tt * (16 * GST / 2);
      float s0 = __builtin_amdgcn_rcpf(1.f + __builtin_amdgcn_exp2f(gg[tt][0]));
      float s1 = __builtin_amdgcn_rcpf(1.f + __builtin_amdgcn_exp2f(gg[tt][1]));
      float s2 = __builtin_amdgcn_rcpf(1.f + __builtin_amdgcn_exp2f(gg[tt][2]));
      float s3 = __builtin_amdgcn_rcpf(1.f + __builtin_amdgcn_exp2f(gg[tt][3]));
      gw[0] = pkbf(ga[tt][0] * s0, ga[tt][1] * s1);
      gw[1] = pkbf(ga[tt][2] * s2, ga[tt][3] * s3);
    }
  } else {
#pragma unroll
    for (int tt = 0; tt < 4; ++tt) {
      unsigned* gw = glw0 + tt * (16 * GST / 2);
      float g0 = (mypos + 0 < S) ? ga[tt][0] * __builtin_amdgcn_rcpf(1.f + __builtin_amdgcn_exp2f(gg[tt][0])) : 0.f;
      float g1 = (mypos + 1 < S) ? ga[tt][1] * __builtin_amdgcn_rcpf(1.f + __builtin_amdgcn_exp2f(gg[tt][1])) : 0.f;
      float g2 = (mypos + 2 < S) ? ga[tt][2] * __builtin_amdgcn_rcpf(1.f + __builtin_amdgcn_exp2f(gg[tt][2])) : 0.f;
      float g3 = (mypos + 3 < S) ? ga[tt][3] * __builtin_amdgcn_rcpf(1.f + __builtin_amdgcn_exp2f(gg[tt][3])) : 0.f;
      gw[0] = pkbf(g0, g1);
      gw[1] = pkbf(g2, g3);
    }
  }
}

__device__ __forceinline__ void conv_chunk(const unsigned* glr, const float* tapp,
                                           const unsigned short* fb2p,
                                           unsigned short* sbw, const unsigned short* sbr,
                                           int mt, f32x4 (&acc2)[2]) {
  const float4 t0 = *reinterpret_cast<const float4*>(tapp);
  const float4 t1 = *reinterpret_cast<const float4*>(tapp + 4);
  const float4 t2 = *reinterpret_cast<const float4*>(tapp + 8);
  // hoisted pair-broadcast taps (built ONCE per chunk - R19 fix)
  f32x2 tp[9];
  tp[0] = (f32x2){t0.x, t0.x}; tp[1] = (f32x2){t0.y, t0.y};
  tp[2] = (f32x2){t0.z, t0.z}; tp[3] = (f32x2){t0.w, t0.w};
  tp[4] = (f32x2){t1.x, t1.x}; tp[5] = (f32x2){t1.y, t1.y};
  tp[6] = (f32x2){t1.z, t1.z}; tp[7] = (f32x2){t1.w, t1.w};
  tp[8] = (f32x2){t2.x, t2.x};
  const f32x2 shp = (f32x2){t2.y, t2.y};
  float gv[24];
#pragma unroll
  for (int i2 = 0; i2 < 12; ++i2) {
    const unsigned d = glr[i2];
    gv[2 * i2]     = bflo(d);
    gv[2 * i2 + 1] = bfhi(d);
  }
  f32x2 q[16];
#pragma unroll
  for (int j = 0; j < 16; ++j) q[j] = (f32x2){gv[j], gv[j + 8]};
#pragma unroll
  for (int i2 = 0; i2 < 8; ++i2) {
    f32x2 ac = shp;
#pragma unroll
    for (int k = 0; k < KW; ++k) ac = ac + q[i2 + k] * tp[k];  // contracts to (pk_)fma
    const float a0 = ac.x, a1 = ac.y;
    const float s0 = a0 * __builtin_amdgcn_rcpf(1.f + __builtin_amdgcn_exp2f(a0 * NLOG2E));
    const float s1 = a1 * __builtin_amdgcn_rcpf(1.f + __builtin_amdgcn_exp2f(a1 * NLOG2E));
    sbw[i2 * 72] = f2bf(s0);
    unsigned short hv = f2bf(s1);
    if (mt == 3 && i2 >= 3) hv = 0;   // pos >= 59 masked
    sbw[(i2 + 8) * 72] = hv;
  }
#pragma unroll
  for (int kt = 0; kt < 2; ++kt) {
    short8 a2f = *reinterpret_cast<const short8*>(sbr + kt * 32);
#pragma unroll
    for (int nt = 0; nt < 2; ++nt) {
      short8 b2f = *reinterpret_cast<const short8*>(fb2p + (kt * 2 + nt) * 512);
      acc2[nt] = __builtin_amdgcn_mfma_f32_16x16x32_bf16(a2f, b2f, acc2[nt], 0, 0, 0);
    }
  }
}

__global__ __launch_bounds__(512) void k_conv(
    const float* __restrict__ pep, const float* __restrict__ mhc,
    const unsigned short* __restrict__ FB1, const unsigned short* __restrict__ FB2,
    const float* __restrict__ TAP, float* __restrict__ Yp) {
  __shared__ __align__(16) unsigned char smem[2 * 64 * GST * 2 + 4 * 16 * 72 * 2];  // 28160 B
  unsigned short* Xbf = reinterpret_cast<unsigned short*>(smem);   // [64][40] setup overlay
  unsigned short* glA = reinterpret_cast<unsigned short*>(smem);   // [64][GST]
  unsigned short* glB = glA + 64 * GST;                            // [64][GST]
  unsigned short* Sb  = glB + 64 * GST;                            // [4][16*72]
  const int t = threadIdx.x;
  const int b = blockIdx.x >> 1;
  const int half = blockIdx.x & 1;
  const int lane = t & 63;
  const int w = t >> 6;          // 0-3 GLU producers, 4-7 conv consumers
  const int lr = lane & 15;
  const int lg = lane >> 4;
  const bool isGlu = (w < 4);
  const int mt = isGlu ? w : (w - 4);   // M-tile this wave owns
  const int mypos = mt * 16 + lg * 4;

  // ---- phase A: X -> bf16 (first 256 threads; rows>=59/cols>=21 zero; col21=1.0) ----
  if (t < 256) {
    const int row = t >> 2, qq = t & 3;
    const float* xr = (row < PEP) ? pep + ((size_t)b * PEP + row) * V
                    : (row < S)   ? mhc + ((size_t)b * MHCN + (row - PEP)) * V
                                  : nullptr;
#pragma unroll
    for (int i2 = 0; i2 < 5; ++i2) {
      int c0 = qq * 10 + 2 * i2;
      float f0 = (xr && c0 < V) ? xr[c0] : 0.f;
      float f1 = (xr && c0 + 1 < V) ? xr[c0 + 1] : ((xr && c0 + 1 == V) ? 1.f : 0.f);
      *reinterpret_cast<unsigned*>(&Xbf[row * 40 + c0]) = pkbf(f0, f1);
    }
  }
  __syncthreads();

  short8 ax = {};
  if (isGlu) ax = *reinterpret_cast<const short8*>(&Xbf[(mt * 16 + lr) * 40 + lg * 8]);
  __syncthreads();  // Xbf dead; glA may now be overwritten

  // ---- zero left halos of BOTH buffers (first 256 threads: 64 rows x 2 dw x 2 buf) ----
  if (t < 256) {
    unsigned short* buf = (t < 128) ? glA : glB;
    const int i2 = t & 127;
    *reinterpret_cast<unsigned*>(&buf[(i2 >> 1) * GST + (i2 & 1) * 2]) = 0u;
  }

  f32x4 acc2[2];
  acc2[0] = (f32x4){0.f, 0.f, 0.f, 0.f};
  acc2[1] = (f32x4){0.f, 0.f, 0.f, 0.f};

  // loop-invariant addresses
  unsigned* glwA = reinterpret_cast<unsigned*>(&glA[lr * GST + 4 + mypos]);
  unsigned* glwB = reinterpret_cast<unsigned*>(&glB[lr * GST + 4 + mypos]);
  const unsigned* glrA = reinterpret_cast<const unsigned*>(&glA[lane * GST + mt * 16]);
  const unsigned* glrB = reinterpret_cast<const unsigned*>(&glB[lane * GST + mt * 16]);
  unsigned short* sbw = Sb + mt * (16 * 72) + lane;
  const unsigned short* sbr = Sb + mt * (16 * 72) + lr * 72 + lg * 8;
  const unsigned short* fb1p = FB1 + (size_t)half * CHALF * 8 * 512 + lane * 8;
  const unsigned short* fb2p = FB2 + (size_t)half * CHALF * 4 * 512 + lane * 8;
  const float* tapp = TAP + ((size_t)half * CHALF * 64 + lane) * 12;

  // ---- prologue: GLU(chunk 0) -> A ----
  if (isGlu) glu_chunk(fb1p, glwA, ax, mt, mypos);
  __syncthreads();

  // ---- pipelined pair loop: 1 barrier per chunk; producers fill, consumers drain ----
  for (int p = 0; p < 12; ++p) {
    if (isGlu) glu_chunk(fb1p + 4096, glwB, ax, mt, mypos);            // fill B = 2p+1
    else       conv_chunk(glrA, tapp, fb2p, sbw, sbr, mt, acc2);       // consume A = 2p
    __syncthreads();
    if (isGlu) glu_chunk(fb1p + 2 * 4096, glwA, ax, mt, mypos);        // fill A = 2p+2
    else       conv_chunk(glrB, tapp + 768, fb2p + 2048, sbw, sbr, mt, acc2);  // B = 2p+1
    __syncthreads();
    fb1p += 2 * 4096;
    fb2p += 2 * 2048;
    tapp += 2 * 768;
  }
  // ---- epilogue: consume A = chunk 24 ----
  if (!isGlu) {
    conv_chunk(glrA, tapp, fb2p, sbw, sbr, mt, acc2);
    // ---- write partial down-proj to global (plain stores, deterministic) ----
    float* yp = Yp + (size_t)blockIdx.x * SV;
#pragma unroll
    for (int nt = 0; nt < 2; ++nt) {
#pragma unroll
      for (int r = 0; r < 4; ++r) {
        const int pos = mypos + r, vc = nt * 16 + lr;
        if (pos < S && vc < V) yp[pos * V + vc] = acc2[nt][r];
      }
    }
  }
}

// ---------------- K3: fused LN + MFMA attention + Wo + residual + LN -> X2bf ----------------
// Prologue absorbs k_ln: X1f = LN(residual + sum of 2 Yp partials + b2).
__global__ __launch_bounds__(256) void k_attn(
    const float* __restrict__ pep, const float* __restrict__ mhc,
    const float* __restrict__ Yp, const float* __restrict__ b2,
    const unsigned short* __restrict__ FQKV,
    const unsigned short* __restrict__ FWo, const float* __restrict__ lng,
    const float* __restrict__ lnb, unsigned short* __restrict__ X2bf) {
  __shared__ float X1f[64 * 21];
  __shared__ __align__(16) unsigned short Qb[64 * 40];
  __shared__ __align__(16) unsigned short Kb[64 * 40];
  __shared__ __align__(16) unsigned short Vt[32 * 72];
  __shared__ __align__(16) unsigned short Pt[64 * 72];
  __shared__ __align__(16) unsigned short Oh[64 * 40];
  const int t = threadIdx.x;
  const int b = blockIdx.x;
  const int lane = t & 63;
  const int w = t >> 6;
  const int lr = lane & 15;
  const int lg = lane >> 4;
  const int mypos = w * 16 + lg * 4;

  // ---- prologue: conv-module LN (fused k_ln) -> X1f ----
  if (t < 64) {
    if (t < S) {
      const float* xr = (t < PEP) ? pep + ((size_t)b * PEP + t) * V
                                  : mhc + ((size_t)b * MHCN + (t - PEP)) * V;
      const float* y0 = Yp + (size_t)(2 * b) * SV + t * V;
      float z[V];
      float mn = 0.f;
#pragma unroll
      for (int v = 0; v < V; ++v) {
        z[v] = xr[v] + (y0[v] + y0[SV + v]) + b2[v];
        mn += z[v];
      }
      mn *= (1.f / V);
      float var = 0.f;
#pragma unroll
      for (int v = 0; v < V; ++v) {
        float d = z[v] - mn;
        var = fmaf(d, d, var);
      }
      const float inv = rsqrtf(var * (1.f / V) + EPSF);
#pragma unroll
      for (int v = 0; v < V; ++v)
        X1f[t * 21 + v] = (z[v] - mn) * inv * lng[v] + lnb[v];
    } else {
#pragma unroll
      for (int v = 0; v < V; ++v) X1f[t * 21 + v] = 0.f;
    }
  }
  __syncthreads();

  short8 ax;
  {
    const int rowi = w * 16 + lr;
#pragma unroll
    for (int j = 0; j < 8; ++j) {
      int col = lg * 8 + j;
      ax[j] = (short)((col < V) ? f2bf(X1f[rowi * 21 + col]) : (unsigned short)0);
    }
  }
  f32x4 accw[2];
  accw[0] = (f32x4){0.f, 0.f, 0.f, 0.f};
  accw[1] = (f32x4){0.f, 0.f, 0.f, 0.f};

  for (int h = 0; h < H; ++h) {
    const unsigned short* fq = FQKV + (size_t)(h * 6) * 512;
    f32x4 dq[2], dk[2], dv[2];
#pragma unroll
    for (int nt = 0; nt < 2; ++nt) {
      short8 bq = *reinterpret_cast<const short8*>(fq + (0 + nt) * 512 + lane * 8);
      dq[nt] = __builtin_amdgcn_mfma_f32_16x16x32_bf16(ax, bq, (f32x4){0.f, 0.f, 0.f, 0.f}, 0, 0, 0);
      short8 bk = *reinterpret_cast<const short8*>(fq + (2 + nt) * 512 + lane * 8);
      dk[nt] = __builtin_amdgcn_mfma_f32_16x16x32_bf16(ax, bk, (f32x4){0.f, 0.f, 0.f, 0.f}, 0, 0, 0);
      short8 bv = *reinterpret_cast<const short8*>(fq + (4 + nt) * 512 + lane * 8);
      dv[nt] = __builtin_amdgcn_mfma_f32_16x16x32_bf16(ax, bv, (f32x4){0.f, 0.f, 0.f, 0.f}, 0, 0, 0);
    }
#pragma unroll
    for (int nt = 0; nt < 2; ++nt) {
      const int d = nt * 16 + lr;
#pragma unroll
      for (int r = 0; r < 4; ++r) {
        const int pos = mypos + r;
        Qb[pos * 40 + d] = f2bf(dq[nt][r]);
        Kb[pos * 40 + d] = f2bf(dk[nt][r]);
      }
      // Vt row d: positions mypos..mypos+3 contiguous -> 2 packed dwords
      *reinterpret_cast<unsigned*>(&Vt[d * 72 + mypos])     = pkbf(dv[nt][0], dv[nt][1]);
      *reinterpret_cast<unsigned*>(&Vt[d * 72 + mypos + 2]) = pkbf(dv[nt][2], dv[nt][3]);
    }
    __syncthreads();  // bar1: Qb/Kb/Vt complete

    short8 bqf = *reinterpret_cast<const short8*>(&Qb[(w * 16 + lr) * 40 + lg * 8]);
    f32x4 st[4];
#pragma unroll
    for (int mt = 0; mt < 4; ++mt) {
      short8 akf = *reinterpret_cast<const short8*>(&Kb[(mt * 16 + lr) * 40 + lg * 8]);
      st[mt] = __builtin_amdgcn_mfma_f32_16x16x32_bf16(akf, bqf, (f32x4){0.f, 0.f, 0.f, 0.f}, 0, 0, 0);
    }
    float mx = -1e30f;
#pragma unroll
    for (int mt = 0; mt < 4; ++mt)
#pragma unroll
      for (int r = 0; r < 4; ++r) {
        const int j = mt * 16 + lg * 4 + r;
        float sv = (j < S) ? st[mt][r] : -1e30f;
        st[mt][r] = sv;
        mx = fmaxf(mx, sv);
      }
    mx = fmaxf(mx, __shfl_xor(mx, 16));
    mx = fmaxf(mx, __shfl_xor(mx, 32));
    float sum = 0.f;
#pragma unroll
    for (int mt = 0; mt < 4; ++mt)
#pragma unroll
      for (int r = 0; r < 4; ++r) {
        float e = __expf(st[mt][r] - mx);
        st[mt][r] = e;
        sum += e;
      }
    sum += __shfl_xor(sum, 16);
    sum += __shfl_xor(sum, 32);
#pragma unroll
    for (int mt = 0; mt < 4; ++mt) {
#pragma unroll
      for (int s2 = 0; s2 < 2; ++s2) {
        *reinterpret_cast<unsigned*>(&Pt[(w * 16 + lr) * 72 + mt * 16 + lg * 4 + 2 * s2]) =
            pkbf(st[mt][2 * s2], st[mt][2 * s2 + 1]);
      }
    }
    short8 bp0 = *reinterpret_cast<const short8*>(&Pt[(w * 16 + lr) * 72 + lg * 8]);
    short8 bp1 = *reinterpret_cast<const short8*>(&Pt[(w * 16 + lr) * 72 + 32 + lg * 8]);
    f32x4 ot[2];
    ot[0] = (f32x4){0.f, 0.f, 0.f, 0.f};
    ot[1] = (f32x4){0.f, 0.f, 0.f, 0.f};
#pragma unroll
    for (int mt = 0; mt < 2; ++mt) {
      short8 av0 = *reinterpret_cast<const short8*>(&Vt[(mt * 16 + lr) * 72 + lg * 8]);
      ot[mt] = __builtin_amdgcn_mfma_f32_16x16x32_bf16(av0, bp0, ot[mt], 0, 0, 0);
      short8 av1 = *reinterpret_cast<const short8*>(&Vt[(mt * 16 + lr) * 72 + 32 + lg * 8]);
      ot[mt] = __builtin_amdgcn_mfma_f32_16x16x32_bf16(av1, bp1, ot[mt], 0, 0, 0);
    }
    const float inv = __builtin_amdgcn_rcpf(sum);
#pragma unroll
    for (int mt = 0; mt < 2; ++mt) {
#pragma unroll
      for (int s2 = 0; s2 < 2; ++s2) {
        *reinterpret_cast<unsigned*>(&Oh[(w * 16 + lr) * 40 + mt * 16 + lg * 4 + 2 * s2]) =
            pkbf(ot[mt][2 * s2] * inv, ot[mt][2 * s2 + 1] * inv);
      }
    }
    short8 ao = *reinterpret_cast<const short8*>(&Oh[(w * 16 + lr) * 40 + lg * 8]);
#pragma unroll
    for (int nt = 0; nt < 2; ++nt) {
      short8 bw = *reinterpret_cast<const short8*>(FWo + (size_t)(h * 2 + nt) * 512 + lane * 8);
      accw[nt] = __builtin_amdgcn_mfma_f32_16x16x32_bf16(ao, bw, accw[nt], 0, 0, 0);
    }
    __syncthreads();  // bar2
  }

  // ---- epilogue: residual + LayerNorm -> X2bf (bf16, padded to XF) ----
#pragma unroll
  for (int r = 0; r < 4; ++r) {
    const int pos = mypos + r;
    const bool v1ok = (lr < 5);
    const float x0 = (pos < S) ? X1f[pos * 21 + lr] : 0.f;
    const float x1 = (v1ok && pos < S) ? X1f[pos * 21 + 16 + lr] : 0.f;
    float z0 = accw[0][r] + x0;
    float z1 = v1ok ? (accw[1][r] + x1) : 0.f;
    float s = z0 + z1;
    s += __shfl_xor(s, 1); s += __shfl_xor(s, 2);
    s += __shfl_xor(s, 4); s += __shfl_xor(s, 8);
    const float mn = s * (1.f / V);
    const float d0 = z0 - mn;
    const float d1 = v1ok ? (z1 - mn) : 0.f;
    float vq = d0 * d0 + d1 * d1;
    vq += __shfl_xor(vq, 1); vq += __shfl_xor(vq, 2);
    vq += __shfl_xor(vq, 4); vq += __shfl_xor(vq, 8);
    const float inv = rsqrtf(vq * (1.f / V) + EPSF);
    if (pos < S) {
      X2bf[(size_t)b * XF + pos * 21 + lr] = f2bf(d0 * inv * lng[lr] + lnb[lr]);
      if (v1ok)
        X2bf[(size_t)b * XF + pos * 21 + 16 + lr] = f2bf(d1 * inv * lng[16 + lr] + lnb[16 + lr]);
    }
  }
  if (t < XF - SV) X2bf[(size_t)b * XF + SV + t] = 0;  // zero K-pad
}

// ---------------- K5: MFMA head GEMM [1024,1248bf]@[1248,800] + silu + BN -> Hb ----------------
// grid (16,10): block = 64 rows x 80 cols; wave = 16-row strip x 5 N-tiles.
__global__ __launch_bounds__(256) void k_f1(
    const unsigned short* __restrict__ X2bf, const unsigned short* __restrict__ FWf1,
    const float* __restrict__ bf1, const float* __restrict__ g2,
    const float* __restrict__ bb2, const float* __restrict__ m2,
    const float* __restrict__ v2, float* __restrict__ Hb) {
  const int t = threadIdx.x;
  const int lane = t & 63;
  const int w = t >> 6;
  const int lr = lane & 15;
  const int lg = lane >> 4;
  const int Mb = blockIdx.x * 64;
  const int NbT = blockIdx.y * 5;  // N-tile base (80 cols)

  const unsigned short* ap = X2bf + (size_t)(Mb + w * 16 + lr) * XF + lg * 8;
  const unsigned short* bp = FWf1 + (size_t)NbT * 39 * 512 + lane * 8;
  f32x4 acc[5];
#pragma unroll
  for (int nt = 0; nt < 5; ++nt) acc[nt] = (f32x4){0.f, 0.f, 0.f, 0.f};

  for (int kk = 0; kk < 39; ++kk) {
    short8 af = *reinterpret_cast<const short8*>(ap + kk * 32);
#pragma unroll
    for (int nt = 0; nt < 5; ++nt) {
      short8 bf = *reinterpret_cast<const short8*>(bp + ((size_t)nt * 39 + kk) * 512);
      acc[nt] = __builtin_amdgcn_mfma_f32_16x16x32_bf16(af, bf, acc[nt], 0, 0, 0);
    }
  }
#pragma unroll
  for (int nt = 0; nt < 5; ++nt) {
    const int n = (NbT + nt) * 16 + lr;
    const float sc = g2[n] * rsqrtf(v2[n] + EPSF);
    const float sh = bb2[n] - m2[n] * sc;
    const float bias = bf1[n];
#pragma unroll
    for (int r = 0; r < 4; ++r) {
      const int row = Mb + w * 16 + lg * 4 + r;
      float hh = acc[nt][r] + bias;
      hh = fmaf(hh * sigm(hh), sc, sh);
      Hb[(size_t)row * NH + n] = hh;
    }
  }
}

// ---------------- K6: relu(Hb@Wf2+bf2) @ Wf3 + bf3 -> out [B,2] ----------------
__global__ __launch_bounds__(64) void k_f23(
    const float* __restrict__ Hb, const float* __restrict__ Wf2, const float* __restrict__ bf2,
    const float* __restrict__ Wf3, const float* __restrict__ bf3, float* __restrict__ out) {
  __shared__ __align__(16) float hs[NH];
  const int t = threadIdx.x;
  const int b = blockIdx.x;
  for (int i = t; i < NH; i += 64) hs[i] = Hb[(size_t)b * NH + i];
  __syncthreads();
  float acc = bf2[t];
  for (int n = 0; n < NH; n += 4) {
    const float4 hv = *reinterpret_cast<const float4*>(&hs[n]);
    acc = fmaf(hv.x, Wf2[n * 64 + t], acc);
    acc = fmaf(hv.y, Wf2[(n + 1) * 64 + t], acc);
    acc = fmaf(hv.z, Wf2[(n + 2) * 64 + t], acc);
    acc = fmaf(hv.w, Wf2[(n + 3) * 64 + t], acc);
  }
  const float mid = fmaxf(acc, 0.f);
  float p0 = mid * Wf3[t * 2 + 0];
  float p1 = mid * Wf3[t * 2 + 1];
#pragma unroll
  for (int off = 32; off > 0; off >>= 1) {
    p0 += __shfl_down(p0, off);
    p1 += __shfl_down(p1, off);
  }
  if (t == 0) {
    out[b * 2 + 0] = p0 + bf3[0];
    out[b * 2 + 1] = p1 + bf3[1];
  }
}

}  // namespace

extern "C" void kernel_launch(void* const* d_in, const int* in_sizes, int n_in,
                              void* d_out, int out_size, void* d_ws, size_t ws_size,
                              hipStream_t stream) {
  const float* pep   = (const float*)d_in[0];
  const float* mhc   = (const float*)d_in[1];
  const float* W1    = (const float*)d_in[2];
  const float* b1    = (const float*)d_in[3];
  const float* Wd    = (const float*)d_in[4];
  const float* bd    = (const float*)d_in[5];
  const float* bn1_g = (const float*)d_in[6];
  const float* bn1_b = (const float*)d_in[7];
  const float* bn1_m = (const float*)d_in[8];
  const float* bn1_v = (const float*)d_in[9];
  const float* W2    = (const float*)d_in[10];
  const float* b2    = (const float*)d_in[11];
  const float* ln_g  = (const float*)d_in[12];
  const float* ln_b  = (const float*)d_in[13];
  const float* Wq    = (const float*)d_in[14];
  const float* Wk    = (const float*)d_in[15];
  const float* Wv    = (const float*)d_in[16];
  const float* Wo    = (const float*)d_in[17];
  const float* Wf1   = (const float*)d_in[18];
  const float* bf1   = (const float*)d_in[19];
  const float* bn2_g = (const float*)d_in[20];
  const float* bn2_b = (const float*)d_in[21];
  const float* bn2_m = (const float*)d_in[22];
  const float* bn2_v = (const float*)d_in[23];
  const float* Wf2   = (const float*)d_in[24];
  const float* bf2   = (const float*)d_in[25];
  const float* Wf3   = (const float*)d_in[26];
  const float* bf3   = (const float*)d_in[27];
  float* out = (float*)d_out;

  float* ws = (float*)d_ws;
  unsigned short* X2bf = (unsigned short*)ws;                // [B,XF] bf16
  float* Hb = (float*)(X2bf + (size_t)B * XF);               // [B,NH] f32
  float* TAP = Hb + (size_t)B * NH;                          // [C,12]
  unsigned short* FB1  = (unsigned short*)(TAP + (size_t)C * 12);
  unsigned short* FB2  = FB1 + (size_t)400 * 512;
  unsigned short* FQKV = FB2 + (size_t)200 * 512;
  unsigned short* FWo  = FQKV + (size_t)54 * 512;
  unsigned short* FWf1 = FWo + (size_t)18 * 512;             // 1950 x 512 bf16
  float* Yp = (float*)(FWf1 + (size_t)1950 * 512);           // [2B][SV]

  k_packW<<<669, 256, 0, stream>>>(W1, b1, Wd, bd, bn1_g, bn1_b, bn1_m, bn1_v, W2,
                                   Wq, Wk, Wv, Wo, Wf1, FB1, FB2, FQKV, FWo, FWf1, TAP);
  k_conv<<<2 * B, 512, 0, stream>>>(pep, mhc, FB1, FB2, TAP, Yp);
  k_attn<<<B, 256, 0, stream>>>(pep, mhc, Yp, b2, FQKV, FWo, ln_g, ln_b, X2bf);
  dim3 g5(16, 10);
  k_f1<<<g5, 256, 0, stream>>>(X2bf, FWf1, bf1, bn2_g, bn2_b, bn2_m, bn2_v, Hb);
  k_f23<<<B, 64, 0, stream>>>(Hb, Wf2, bf2, Wf3, bf3, out);
}

// Round 20
// 241.183 us; speedup vs baseline: 1.0616x; 1.0014x over previous
//
#include <hip/hip_runtime.h>
#include <hip/hip_bf16.h>

namespace {

constexpr int B   = 1024;
constexpr int PEP = 15;
constexpr int MHCN = 44;
constexpr int S   = 59;    // sequence
constexpr int V   = 21;    // vocab / model dim
constexpr int C   = 3200;  // conv channels
constexpr int KW  = 9;     // depthwise kernel
constexpr int H   = 9;     // heads
constexpr int NH  = 800;
constexpr int SV  = S * V;   // 1239
constexpr int HD  = H * V;   // 189
constexpr int XF  = 1248;    // X2bf padded feature count (39*32)
constexpr float EPSF = 1e-5f;
constexpr int CHALF = 25;    // conv chunks per half-block
constexpr float NLOG2E = -1.4426950408889634f;

typedef __attribute__((ext_vector_type(8))) short short8;   // 8 bf16 (4 VGPRs)
typedef __attribute__((ext_vector_type(4))) float f32x4;    // MFMA C/D frag
typedef __attribute__((ext_vector_type(2))) float f32x2;    // packed-f32 pair

__device__ __forceinline__ float sigm(float x) {
  return __builtin_amdgcn_rcpf(1.f + __expf(-x));
}
// single-instruction f32->bf16 (RNE) via cvt_pk; low 16 bits = cvt(src0)
__device__ __forceinline__ unsigned short f2bf(float f) {
  unsigned r;
  asm("v_cvt_pk_bf16_f32 %0, %1, %2" : "=v"(r) : "v"(f), "v"(f));
  return (unsigned short)r;
}
__device__ __forceinline__ unsigned pkbf(float a, float b) {
  unsigned r;
  asm("v_cvt_pk_bf16_f32 %0, %1, %2" : "=v"(r) : "v"(a), "v"(b));
  return r;  // a in low 16, b in high 16
}
__device__ __forceinline__ float bflo(unsigned d) {
  union { unsigned u; float f; } v; v.u = d << 16; return v.f;
}
__device__ __forceinline__ float bfhi(unsigned d) {
  union { unsigned u; float f; } v; v.u = d & 0xffff0000u; return v.f;
}

// ---------------- K0: pack all weights into MFMA B-fragment order (bf16) ----------------
// Frag convention (R8-verified): mfma(Afrag,Bfrag)=A@B^T with A[m=lr][k=lg*8+j],
// B[n=lr][k=lg*8+j], D[row=lg*4+reg][col=lr].  FB1 k=21 slot carries b1.
// g-rows (tt>=4) pre-scaled by -log2(e): sigm(g) = rcp(1+exp2(gs)).
__global__ void k_packW(const float* __restrict__ W1, const float* __restrict__ b1,
                        const float* __restrict__ Wd,
                        const float* __restrict__ bd, const float* __restrict__ g,
                        const float* __restrict__ bb, const float* __restrict__ m,
                        const float* __restrict__ vv, const float* __restrict__ W2,
                        const float* __restrict__ Wq, const float* __restrict__ Wk,
                        const float* __restrict__ Wv, const float* __restrict__ Wo,
                        const float* __restrict__ Wf1,
                        unsigned short* __restrict__ FB1, unsigned short* __restrict__ FB2,
                        unsigned short* __restrict__ FQKV, unsigned short* __restrict__ FWo,
                        unsigned short* __restrict__ FWf1, float* __restrict__ TAP) {
  int id = blockIdx.x * 256 + threadIdx.x;
  if (id < 400 * 64) {                       // FB1 (+bias at k==V); g-rows scaled
    int tau = id >> 6, l = id & 63;
    int ci = tau >> 3, tt = tau & 7;
    int lr = l & 15, lg = l >> 4;
    bool isg = (tt >= 4);
    int row = (!isg) ? (ci * 64 + tt * 16 + lr) : (C + ci * 64 + (tt - 4) * 16 + lr);
    float sc = isg ? NLOG2E : 1.f;
    for (int j = 0; j < 8; ++j) {
      int k = lg * 8 + j;
      float val = (k < V) ? W1[row * V + k] * sc : (k == V ? b1[row] * sc : 0.f);
      FB1[(size_t)tau * 512 + l * 8 + j] = f2bf(val);
    }
  } else if (id < 38400) {                   // FB2
    int id2 = id - 25600;
    int sg = id2 >> 6, l = id2 & 63;
    int ci = sg >> 2, rem = sg & 3, kt = rem >> 1, nt = rem & 1;
    int lr = l & 15, lg = l >> 4;
    int vc = nt * 16 + lr;
    for (int j = 0; j < 8; ++j) {
      int ch = ci * 64 + kt * 32 + lg * 8 + j;
      float val = (vc < V) ? W2[(size_t)vc * C + ch] : 0.f;
      FB2[(size_t)sg * 512 + l * 8 + j] = f2bf(val);
    }
  } else if (id < 41856) {                   // FQKV: 9h x 3mat x 2nt tiles
    int id2 = id - 38400;
    int tile = id2 >> 6, l = id2 & 63;
    int h = tile / 6, rem = tile - h * 6;
    int mat = rem >> 1, nt = rem & 1;
    int lr = l & 15, kg = l >> 4;
    int dcol = nt * 16 + lr;
    const float* W = (mat == 0) ? Wq : (mat == 1) ? Wk : Wv;
    const float scale = (mat == 0) ? 0.21821789023599236f : 1.f;  // 1/sqrt(21) into Q
    for (int j = 0; j < 8; ++j) {
      int u = kg * 8 + j;
      float val = (u < V && dcol < V) ? W[u * HD + h * V + dcol] * scale : 0.f;
      FQKV[(size_t)tile * 512 + l * 8 + j] = f2bf(val);
    }
  } else if (id < 43008) {                   // FWo: 9h x 2nt tiles, k = head-dim d
    int id2 = id - 41856;
    int tile = id2 >> 6, l = id2 & 63;
    int h = tile >> 1, nt = tile & 1;
    int lr = l & 15, kg = l >> 4;
    int vcol = nt * 16 + lr;
    for (int j = 0; j < 8; ++j) {
      int d = kg * 8 + j;
      float val = (d < V && vcol < V) ? Wo[(h * V + d) * V + vcol] : 0.f;
      FWo[(size_t)tile * 512 + l * 8 + j] = f2bf(val);
    }
  } else if (id < 46208) {                   // TAP
    int c = id - 43008;
    if (c < C) {
      float sc = g[c] * rsqrtf(vv[c] + EPSF);
      for (int k = 0; k < KW; ++k) TAP[c * 12 + k] = Wd[c * KW + k] * sc;
      TAP[c * 12 + 9]  = (bd[c] - m[c]) * sc + bb[c];
      TAP[c * 12 + 10] = 0.f;
      TAP[c * 12 + 11] = 0.f;
    }
  } else if (id < 46208 + 1950 * 64) {       // FWf1: 50 ntile x 39 kk tiles
    int id2 = id - 46208;
    int tile = id2 >> 6, l = id2 & 63;
    int ntg = tile / 39, kk = tile - ntg * 39;
    int lr = l & 15, kg = l >> 4;
    int n = ntg * 16 + lr;
    for (int j = 0; j < 8; ++j) {
      int f = kk * 32 + kg * 8 + j;
      float val = (f < SV) ? Wf1[(size_t)f * NH + n] : 0.f;
      FWf1[(size_t)tile * 512 + l * 8 + j] = f2bf(val);
    }
  }
}

// ---------------- K2: MFMA conv module, producer/consumer waves (R20) ----------------
// 512 threads: waves 0-3 GLU producers, waves 4-7 conv consumers; double-buffered
// glbuf, 1 barrier/chunk, hoisted tap pairs. R20: window pairs q[16] built
// DIRECTLY from LDS dwords (no gv[24] intermediate -> no repack movs).
constexpr int GST = 74;  // glbuf row stride (bf16)

__device__ __forceinline__ void glu_chunk(const unsigned short* fb1p, unsigned* glw0,
                                          short8 ax, int mt, int mypos) {
  f32x4 ga[4], gg[4];
#pragma unroll
  for (int tt = 0; tt < 4; ++tt) {
    short8 bf = *reinterpret_cast<const short8*>(fb1p + tt * 512);
    ga[tt] = __builtin_amdgcn_mfma_f32_16x16x32_bf16(ax, bf, (f32x4){0.f, 0.f, 0.f, 0.f}, 0, 0, 0);
  }
#pragma unroll
  for (int tt = 0; tt < 4; ++tt) {
    short8 bf = *reinterpret_cast<const short8*>(fb1p + (4 + tt) * 512);
    gg[tt] = __builtin_amdgcn_mfma_f32_16x16x32_bf16(ax, bf, (f32x4){0.f, 0.f, 0.f, 0.f}, 0, 0, 0);
  }
  if (mt < 3) {
#pragma unroll
    for (int tt = 0; tt < 4; ++tt) {
      unsigned* gw = glw0 + tt * (16 * GST / 2);
      float s0 = __builtin_amdgcn_rcpf(1.f + __builtin_amdgcn_exp2f(gg[tt][0]));
      float s1 = __builtin_amdgcn_rcpf(1.f + __builtin_amdgcn_exp2f(gg[tt][1]));
      float s2 = __builtin_amdgcn_rcpf(1.f + __builtin_amdgcn_exp2f(gg[tt][2]));
      float s3 = __builtin_amdgcn_rcpf(1.f + __builtin_amdgcn_exp2f(gg[tt][3]));
      gw[0] = pkbf(ga[tt][0] * s0, ga[tt][1] * s1);
      gw[1] = pkbf(ga[tt][2] * s2, ga[tt][3] * s3);
    }
  } else {
#pragma unroll
    for (int tt = 0; tt < 4; ++tt) {
      unsigned* gw = glw0 + tt * (16 * GST / 2);
      float g0 = (mypos + 0 < S) ? ga[tt][0] * __builtin_amdgcn_rcpf(1.f + __builtin_amdgcn_exp2f(gg[tt][0])) : 0.f;
      float g1 = (mypos + 1 < S) ? ga[tt][1] * __builtin_amdgcn_rcpf(1.f + __builtin_amdgcn_exp2f(gg[tt][1])) : 0.f;
      float g2 = (mypos + 2 < S) ? ga[tt][2] * __builtin_amdgcn_rcpf(1.f + __builtin_amdgcn_exp2f(gg[tt][2])) : 0.f;
      float g3 = (mypos + 3 < S) ? ga[tt][3] * __builtin_amdgcn_rcpf(1.f + __builtin_amdgcn_exp2f(gg[tt][3])) : 0.f;
      gw[0] = pkbf(g0, g1);
      gw[1] = pkbf(g2, g3);
    }
  }
}

__device__ __forceinline__ void conv_chunk(const unsigned* glr, const float* tapp,
                                           const unsigned short* fb2p,
                                           unsigned short* sbw, const unsigned short* sbr,
                                           int mt, f32x4 (&acc2)[2]) {
  const float4 t0 = *reinterpret_cast<const float4*>(tapp);
  const float4 t1 = *reinterpret_cast<const float4*>(tapp + 4);
  const float4 t2 = *reinterpret_cast<const float4*>(tapp + 8);
  // hoisted pair-broadcast taps (built ONCE per chunk)
  f32x2 tp[9];
  tp[0] = (f32x2){t0.x, t0.x}; tp[1] = (f32x2){t0.y, t0.y};
  tp[2] = (f32x2){t0.z, t0.z}; tp[3] = (f32x2){t0.w, t0.w};
  tp[4] = (f32x2){t1.x, t1.x}; tp[5] = (f32x2){t1.y, t1.y};
  tp[6] = (f32x2){t1.z, t1.z}; tp[7] = (f32x2){t1.w, t1.w};
  tp[8] = (f32x2){t2.x, t2.x};
  const f32x2 shp = (f32x2){t2.y, t2.y};
  // R20: build window pairs directly from the 12 LDS dwords:
  //   q[2i]   = { bflo(d[i]), bflo(d[i+4]) }
  //   q[2i+1] = { bfhi(d[i]), bfhi(d[i+4]) }   (i = 0..7)
  unsigned d[12];
#pragma unroll
  for (int i2 = 0; i2 < 12; ++i2) d[i2] = glr[i2];
  f32x2 q[16];
#pragma unroll
  for (int i2 = 0; i2 < 8; ++i2) {
    q[2 * i2]     = (f32x2){bflo(d[i2]), bflo(d[i2 + 4])};
    q[2 * i2 + 1] = (f32x2){bfhi(d[i2]), bfhi(d[i2 + 4])};
  }
#pragma unroll
  for (int i2 = 0; i2 < 8; ++i2) {
    f32x2 ac = shp;
#pragma unroll
    for (int k = 0; k < KW; ++k) ac = ac + q[i2 + k] * tp[k];  // contracts to (pk_)fma
    const float a0 = ac.x, a1 = ac.y;
    const float s0 = a0 * __builtin_amdgcn_rcpf(1.f + __builtin_amdgcn_exp2f(a0 * NLOG2E));
    const float s1 = a1 * __builtin_amdgcn_rcpf(1.f + __builtin_amdgcn_exp2f(a1 * NLOG2E));
    sbw[i2 * 72] = f2bf(s0);
    unsigned short hv = f2bf(s1);
    if (mt == 3 && i2 >= 3) hv = 0;   // pos >= 59 masked
    sbw[(i2 + 8) * 72] = hv;
  }
#pragma unroll
  for (int kt = 0; kt < 2; ++kt) {
    short8 a2f = *reinterpret_cast<const short8*>(sbr + kt * 32);
#pragma unroll
    for (int nt = 0; nt < 2; ++nt) {
      short8 b2f = *reinterpret_cast<const short8*>(fb2p + (kt * 2 + nt) * 512);
      acc2[nt] = __builtin_amdgcn_mfma_f32_16x16x32_bf16(a2f, b2f, acc2[nt], 0, 0, 0);
    }
  }
}

__global__ __launch_bounds__(512) void k_conv(
    const float* __restrict__ pep, const float* __restrict__ mhc,
    const unsigned short* __restrict__ FB1, const unsigned short* __restrict__ FB2,
    const float* __restrict__ TAP, float* __restrict__ Yp) {
  __shared__ __align__(16) unsigned char smem[2 * 64 * GST * 2 + 4 * 16 * 72 * 2];  // 28160 B
  unsigned short* Xbf = reinterpret_cast<unsigned short*>(smem);   // [64][40] setup overlay
  unsigned short* glA = reinterpret_cast<unsigned short*>(smem);   // [64][GST]
  unsigned short* glB = glA + 64 * GST;                            // [64][GST]
  unsigned short* Sb  = glB + 64 * GST;                            // [4][16*72]
  const int t = threadIdx.x;
  const int b = blockIdx.x >> 1;
  const int half = blockIdx.x & 1;
  const int lane = t & 63;
  const int w = t >> 6;          // 0-3 GLU producers, 4-7 conv consumers
  const int lr = lane & 15;
  const int lg = lane >> 4;
  const bool isGlu = (w < 4);
  const int mt = isGlu ? w : (w - 4);   // M-tile this wave owns
  const int mypos = mt * 16 + lg * 4;

  // ---- phase A: X -> bf16 (first 256 threads; rows>=59/cols>=21 zero; col21=1.0) ----
  if (t < 256) {
    const int row = t >> 2, qq = t & 3;
    const float* xr = (row < PEP) ? pep + ((size_t)b * PEP + row) * V
                    : (row < S)   ? mhc + ((size_t)b * MHCN + (row - PEP)) * V
                                  : nullptr;
#pragma unroll
    for (int i2 = 0; i2 < 5; ++i2) {
      int c0 = qq * 10 + 2 * i2;
      float f0 = (xr && c0 < V) ? xr[c0] : 0.f;
      float f1 = (xr && c0 + 1 < V) ? xr[c0 + 1] : ((xr && c0 + 1 == V) ? 1.f : 0.f);
      *reinterpret_cast<unsigned*>(&Xbf[row * 40 + c0]) = pkbf(f0, f1);
    }
  }
  __syncthreads();

  short8 ax = {};
  if (isGlu) ax = *reinterpret_cast<const short8*>(&Xbf[(mt * 16 + lr) * 40 + lg * 8]);
  __syncthreads();  // Xbf dead; glA may now be overwritten

  // ---- zero left halos of BOTH buffers (first 256 threads: 64 rows x 2 dw x 2 buf) ----
  if (t < 256) {
    unsigned short* buf = (t < 128) ? glA : glB;
    const int i2 = t & 127;
    *reinterpret_cast<unsigned*>(&buf[(i2 >> 1) * GST + (i2 & 1) * 2]) = 0u;
  }

  f32x4 acc2[2];
  acc2[0] = (f32x4){0.f, 0.f, 0.f, 0.f};
  acc2[1] = (f32x4){0.f, 0.f, 0.f, 0.f};

  // loop-invariant addresses
  unsigned* glwA = reinterpret_cast<unsigned*>(&glA[lr * GST + 4 + mypos]);
  unsigned* glwB = reinterpret_cast<unsigned*>(&glB[lr * GST + 4 + mypos]);
  const unsigned* glrA = reinterpret_cast<const unsigned*>(&glA[lane * GST + mt * 16]);
  const unsigned* glrB = reinterpret_cast<const unsigned*>(&glB[lane * GST + mt * 16]);
  unsigned short* sbw = Sb + mt * (16 * 72) + lane;
  const unsigned short* sbr = Sb + mt * (16 * 72) + lr * 72 + lg * 8;
  const unsigned short* fb1p = FB1 + (size_t)half * CHALF * 8 * 512 + lane * 8;
  const unsigned short* fb2p = FB2 + (size_t)half * CHALF * 4 * 512 + lane * 8;
  const float* tapp = TAP + ((size_t)half * CHALF * 64 + lane) * 12;

  // ---- prologue: GLU(chunk 0) -> A ----
  if (isGlu) glu_chunk(fb1p, glwA, ax, mt, mypos);
  __syncthreads();

  // ---- pipelined pair loop: 1 barrier per chunk; producers fill, consumers drain ----
  for (int p = 0; p < 12; ++p) {
    if (isGlu) glu_chunk(fb1p + 4096, glwB, ax, mt, mypos);            // fill B = 2p+1
    else       conv_chunk(glrA, tapp, fb2p, sbw, sbr, mt, acc2);       // consume A = 2p
    __syncthreads();
    if (isGlu) glu_chunk(fb1p + 2 * 4096, glwA, ax, mt, mypos);        // fill A = 2p+2
    else       conv_chunk(glrB, tapp + 768, fb2p + 2048, sbw, sbr, mt, acc2);  // B = 2p+1
    __syncthreads();
    fb1p += 2 * 4096;
    fb2p += 2 * 2048;
    tapp += 2 * 768;
  }
  // ---- epilogue: consume A = chunk 24 ----
  if (!isGlu) {
    conv_chunk(glrA, tapp, fb2p, sbw, sbr, mt, acc2);
    // ---- write partial down-proj to global (plain stores, deterministic) ----
    float* yp = Yp + (size_t)blockIdx.x * SV;
#pragma unroll
    for (int nt = 0; nt < 2; ++nt) {
#pragma unroll
      for (int r = 0; r < 4; ++r) {
        const int pos = mypos + r, vc = nt * 16 + lr;
        if (pos < S && vc < V) yp[pos * V + vc] = acc2[nt][r];
      }
    }
  }
}

// ---------------- K3: fused LN + MFMA attention + Wo + residual + LN -> X2bf ----------------
// Prologue absorbs k_ln: X1f = LN(residual + sum of 2 Yp partials + b2).
__global__ __launch_bounds__(256) void k_attn(
    const float* __restrict__ pep, const float* __restrict__ mhc,
    const float* __restrict__ Yp, const float* __restrict__ b2,
    const unsigned short* __restrict__ FQKV,
    const unsigned short* __restrict__ FWo, const float* __restrict__ lng,
    const float* __restrict__ lnb, unsigned short* __restrict__ X2bf) {
  __shared__ float X1f[64 * 21];
  __shared__ __align__(16) unsigned short Qb[64 * 40];
  __shared__ __align__(16) unsigned short Kb[64 * 40];
  __shared__ __align__(16) unsigned short Vt[32 * 72];
  __shared__ __align__(16) unsigned short Pt[64 * 72];
  __shared__ __align__(16) unsigned short Oh[64 * 40];
  const int t = threadIdx.x;
  const int b = blockIdx.x;
  const int lane = t & 63;
  const int w = t >> 6;
  const int lr = lane & 15;
  const int lg = lane >> 4;
  const int mypos = w * 16 + lg * 4;

  // ---- prologue: conv-module LN (fused k_ln) -> X1f ----
  if (t < 64) {
    if (t < S) {
      const float* xr = (t < PEP) ? pep + ((size_t)b * PEP + t) * V
                                  : mhc + ((size_t)b * MHCN + (t - PEP)) * V;
      const float* y0 = Yp + (size_t)(2 * b) * SV + t * V;
      float z[V];
      float mn = 0.f;
#pragma unroll
      for (int v = 0; v < V; ++v) {
        z[v] = xr[v] + (y0[v] + y0[SV + v]) + b2[v];
        mn += z[v];
      }
      mn *= (1.f / V);
      float var = 0.f;
#pragma unroll
      for (int v = 0; v < V; ++v) {
        float d = z[v] - mn;
        var = fmaf(d, d, var);
      }
      const float inv = rsqrtf(var * (1.f / V) + EPSF);
#pragma unroll
      for (int v = 0; v < V; ++v)
        X1f[t * 21 + v] = (z[v] - mn) * inv * lng[v] + lnb[v];
    } else {
#pragma unroll
      for (int v = 0; v < V; ++v) X1f[t * 21 + v] = 0.f;
    }
  }
  __syncthreads();

  short8 ax;
  {
    const int rowi = w * 16 + lr;
#pragma unroll
    for (int j = 0; j < 8; ++j) {
      int col = lg * 8 + j;
      ax[j] = (short)((col < V) ? f2bf(X1f[rowi * 21 + col]) : (unsigned short)0);
    }
  }
  f32x4 accw[2];
  accw[0] = (f32x4){0.f, 0.f, 0.f, 0.f};
  accw[1] = (f32x4){0.f, 0.f, 0.f, 0.f};

  for (int h = 0; h < H; ++h) {
    const unsigned short* fq = FQKV + (size_t)(h * 6) * 512;
    f32x4 dq[2], dk[2], dv[2];
#pragma unroll
    for (int nt = 0; nt < 2; ++nt) {
      short8 bq = *reinterpret_cast<const short8*>(fq + (0 + nt) * 512 + lane * 8);
      dq[nt] = __builtin_amdgcn_mfma_f32_16x16x32_bf16(ax, bq, (f32x4){0.f, 0.f, 0.f, 0.f}, 0, 0, 0);
      short8 bk = *reinterpret_cast<const short8*>(fq + (2 + nt) * 512 + lane * 8);
      dk[nt] = __builtin_amdgcn_mfma_f32_16x16x32_bf16(ax, bk, (f32x4){0.f, 0.f, 0.f, 0.f}, 0, 0, 0);
      short8 bv = *reinterpret_cast<const short8*>(fq + (4 + nt) * 512 + lane * 8);
      dv[nt] = __builtin_amdgcn_mfma_f32_16x16x32_bf16(ax, bv, (f32x4){0.f, 0.f, 0.f, 0.f}, 0, 0, 0);
    }
#pragma unroll
    for (int nt = 0; nt < 2; ++nt) {
      const int d = nt * 16 + lr;
#pragma unroll
      for (int r = 0; r < 4; ++r) {
        const int pos = mypos + r;
        Qb[pos * 40 + d] = f2bf(dq[nt][r]);
        Kb[pos * 40 + d] = f2bf(dk[nt][r]);
      }
      // Vt row d: positions mypos..mypos+3 contiguous -> 2 packed dwords
      *reinterpret_cast<unsigned*>(&Vt[d * 72 + mypos])     = pkbf(dv[nt][0], dv[nt][1]);
      *reinterpret_cast<unsigned*>(&Vt[d * 72 + mypos + 2]) = pkbf(dv[nt][2], dv[nt][3]);
    }
    __syncthreads();  // bar1: Qb/Kb/Vt complete

    short8 bqf = *reinterpret_cast<const short8*>(&Qb[(w * 16 + lr) * 40 + lg * 8]);
    f32x4 st[4];
#pragma unroll
    for (int mt = 0; mt < 4; ++mt) {
      short8 akf = *reinterpret_cast<const short8*>(&Kb[(mt * 16 + lr) * 40 + lg * 8]);
      st[mt] = __builtin_amdgcn_mfma_f32_16x16x32_bf16(akf, bqf, (f32x4){0.f, 0.f, 0.f, 0.f}, 0, 0, 0);
    }
    float mx = -1e30f;
#pragma unroll
    for (int mt = 0; mt < 4; ++mt)
#pragma unroll
      for (int r = 0; r < 4; ++r) {
        const int j = mt * 16 + lg * 4 + r;
        float sv = (j < S) ? st[mt][r] : -1e30f;
        st[mt][r] = sv;
        mx = fmaxf(mx, sv);
      }
    mx = fmaxf(mx, __shfl_xor(mx, 16));
    mx = fmaxf(mx, __shfl_xor(mx, 32));
    float sum = 0.f;
#pragma unroll
    for (int mt = 0; mt < 4; ++mt)
#pragma unroll
      for (int r = 0; r < 4; ++r) {
        float e = __expf(st[mt][r] - mx);
        st[mt][r] = e;
        sum += e;
      }
    sum += __shfl_xor(sum, 16);
    sum += __shfl_xor(sum, 32);
#pragma unroll
    for (int mt = 0; mt < 4; ++mt) {
#pragma unroll
      for (int s2 = 0; s2 < 2; ++s2) {
        *reinterpret_cast<unsigned*>(&Pt[(w * 16 + lr) * 72 + mt * 16 + lg * 4 + 2 * s2]) =
            pkbf(st[mt][2 * s2], st[mt][2 * s2 + 1]);
      }
    }
    short8 bp0 = *reinterpret_cast<const short8*>(&Pt[(w * 16 + lr) * 72 + lg * 8]);
    short8 bp1 = *reinterpret_cast<const short8*>(&Pt[(w * 16 + lr) * 72 + 32 + lg * 8]);
    f32x4 ot[2];
    ot[0] = (f32x4){0.f, 0.f, 0.f, 0.f};
    ot[1] = (f32x4){0.f, 0.f, 0.f, 0.f};
#pragma unroll
    for (int mt = 0; mt < 2; ++mt) {
      short8 av0 = *reinterpret_cast<const short8*>(&Vt[(mt * 16 + lr) * 72 + lg * 8]);
      ot[mt] = __builtin_amdgcn_mfma_f32_16x16x32_bf16(av0, bp0, ot[mt], 0, 0, 0);
      short8 av1 = *reinterpret_cast<const short8*>(&Vt[(mt * 16 + lr) * 72 + 32 + lg * 8]);
      ot[mt] = __builtin_amdgcn_mfma_f32_16x16x32_bf16(av1, bp1, ot[mt], 0, 0, 0);
    }
    const float inv = __builtin_amdgcn_rcpf(sum);
#pragma unroll
    for (int mt = 0; mt < 2; ++mt) {
#pragma unroll
      for (int s2 = 0; s2 < 2; ++s2) {
        *reinterpret_cast<unsigned*>(&Oh[(w * 16 + lr) * 40 + mt * 16 + lg * 4 + 2 * s2]) =
            pkbf(ot[mt][2 * s2] * inv, ot[mt][2 * s2 + 1] * inv);
      }
    }
    short8 ao = *reinterpret_cast<const short8*>(&Oh[(w * 16 + lr) * 40 + lg * 8]);
#pragma unroll
    for (int nt = 0; nt < 2; ++nt) {
      short8 bw = *reinterpret_cast<const short8*>(FWo + (size_t)(h * 2 + nt) * 512 + lane * 8);
      accw[nt] = __builtin_amdgcn_mfma_f32_16x16x32_bf16(ao, bw, accw[nt], 0, 0, 0);
    }
    __syncthreads();  // bar2
  }

  // ---- epilogue: residual + LayerNorm -> X2bf (bf16, padded to XF) ----
#pragma unroll
  for (int r = 0; r < 4; ++r) {
    const int pos = mypos + r;
    const bool v1ok = (lr < 5);
    const float x0 = (pos < S) ? X1f[pos * 21 + lr] : 0.f;
    const float x1 = (v1ok && pos < S) ? X1f[pos * 21 + 16 + lr] : 0.f;
    float z0 = accw[0][r] + x0;
    float z1 = v1ok ? (accw[1][r] + x1) : 0.f;
    float s = z0 + z1;
    s += __shfl_xor(s, 1); s += __shfl_xor(s, 2);
    s += __shfl_xor(s, 4); s += __shfl_xor(s, 8);
    const float mn = s * (1.f / V);
    const float d0 = z0 - mn;
    const float d1 = v1ok ? (z1 - mn) : 0.f;
    float vq = d0 * d0 + d1 * d1;
    vq += __shfl_xor(vq, 1); vq += __shfl_xor(vq, 2);
    vq += __shfl_xor(vq, 4); vq += __shfl_xor(vq, 8);
    const float inv = rsqrtf(vq * (1.f / V) + EPSF);
    if (pos < S) {
      X2bf[(size_t)b * XF + pos * 21 + lr] = f2bf(d0 * inv * lng[lr] + lnb[lr]);
      if (v1ok)
        X2bf[(size_t)b * XF + pos * 21 + 16 + lr] = f2bf(d1 * inv * lng[16 + lr] + lnb[16 + lr]);
    }
  }
  if (t < XF - SV) X2bf[(size_t)b * XF + SV + t] = 0;  // zero K-pad
}

// ---------------- K5: MFMA head GEMM [1024,1248bf]@[1248,800] + silu + BN -> Hb ----------------
// grid (16,10): block = 64 rows x 80 cols; wave = 16-row strip x 5 N-tiles.
__global__ __launch_bounds__(256) void k_f1(
    const unsigned short* __restrict__ X2bf, const unsigned short* __restrict__ FWf1,
    const float* __restrict__ bf1, const float* __restrict__ g2,
    const float* __restrict__ bb2, const float* __restrict__ m2,
    const float* __restrict__ v2, float* __restrict__ Hb) {
  const int t = threadIdx.x;
  const int lane = t & 63;
  const int w = t >> 6;
  const int lr = lane & 15;
  const int lg = lane >> 4;
  const int Mb = blockIdx.x * 64;
  const int NbT = blockIdx.y * 5;  // N-tile base (80 cols)

  const unsigned short* ap = X2bf + (size_t)(Mb + w * 16 + lr) * XF + lg * 8;
  const unsigned short* bp = FWf1 + (size_t)NbT * 39 * 512 + lane * 8;
  f32x4 acc[5];
#pragma unroll
  for (int nt = 0; nt < 5; ++nt) acc[nt] = (f32x4){0.f, 0.f, 0.f, 0.f};

  for (int kk = 0; kk < 39; ++kk) {
    short8 af = *reinterpret_cast<const short8*>(ap + kk * 32);
#pragma unroll
    for (int nt = 0; nt < 5; ++nt) {
      short8 bf = *reinterpret_cast<const short8*>(bp + ((size_t)nt * 39 + kk) * 512);
      acc[nt] = __builtin_amdgcn_mfma_f32_16x16x32_bf16(af, bf, acc[nt], 0, 0, 0);
    }
  }
#pragma unroll
  for (int nt = 0; nt < 5; ++nt) {
    const int n = (NbT + nt) * 16 + lr;
    const float sc = g2[n] * rsqrtf(v2[n] + EPSF);
    const float sh = bb2[n] - m2[n] * sc;
    const float bias = bf1[n];
#pragma unroll
    for (int r = 0; r < 4; ++r) {
      const int row = Mb + w * 16 + lg * 4 + r;
      float hh = acc[nt][r] + bias;
      hh = fmaf(hh * sigm(hh), sc, sh);
      Hb[(size_t)row * NH + n] = hh;
    }
  }
}

// ---------------- K6: relu(Hb@Wf2+bf2) @ Wf3 + bf3 -> out [B,2] ----------------
__global__ __launch_bounds__(64) void k_f23(
    const float* __restrict__ Hb, const float* __restrict__ Wf2, const float* __restrict__ bf2,
    const float* __restrict__ Wf3, const float* __restrict__ bf3, float* __restrict__ out) {
  __shared__ __align__(16) float hs[NH];
  const int t = threadIdx.x;
  const int b = blockIdx.x;
  for (int i = t; i < NH; i += 64) hs[i] = Hb[(size_t)b * NH + i];
  __syncthreads();
  float acc = bf2[t];
  for (int n = 0; n < NH; n += 4) {
    const float4 hv = *reinterpret_cast<const float4*>(&hs[n]);
    acc = fmaf(hv.x, Wf2[n * 64 + t], acc);
    acc = fmaf(hv.y, Wf2[(n + 1) * 64 + t], acc);
    acc = fmaf(hv.z, Wf2[(n + 2) * 64 + t], acc);
    acc = fmaf(hv.w, Wf2[(n + 3) * 64 + t], acc);
  }
  const float mid = fmaxf(acc, 0.f);
  float p0 = mid * Wf3[t * 2 + 0];
  float p1 = mid * Wf3[t * 2 + 1];
#pragma unroll
  for (int off = 32; off > 0; off >>= 1) {
    p0 += __shfl_down(p0, off);
    p1 += __shfl_down(p1, off);
  }
  if (t == 0) {
    out[b * 2 + 0] = p0 + bf3[0];
    out[b * 2 + 1] = p1 + bf3[1];
  }
}

}  // namespace

extern "C" void kernel_launch(void* const* d_in, const int* in_sizes, int n_in,
                              void* d_out, int out_size, void* d_ws, size_t ws_size,
                              hipStream_t stream) {
  const float* pep   = (const float*)d_in[0];
  const float* mhc   = (const float*)d_in[1];
  const float* W1    = (const float*)d_in[2];
  const float* b1    = (const float*)d_in[3];
  const float* Wd    = (const float*)d_in[4];
  const float* bd    = (const float*)d_in[5];
  const float* bn1_g = (const float*)d_in[6];
  const float* bn1_b = (const float*)d_in[7];
  const float* bn1_m = (const float*)d_in[8];
  const float* bn1_v = (const float*)d_in[9];
  const float* W2    = (const float*)d_in[10];
  const float* b2    = (const float*)d_in[11];
  const float* ln_g  = (const float*)d_in[12];
  const float* ln_b  = (const float*)d_in[13];
  const float* Wq    = (const float*)d_in[14];
  const float* Wk    = (const float*)d_in[15];
  const float* Wv    = (const float*)d_in[16];
  const float* Wo    = (const float*)d_in[17];
  const float* Wf1   = (const float*)d_in[18];
  const float* bf1   = (const float*)d_in[19];
  const float* bn2_g = (const float*)d_in[20];
  const float* bn2_b = (const float*)d_in[21];
  const float* bn2_m = (const float*)d_in[22];
  const float* bn2_v = (const float*)d_in[23];
  const float* Wf2   = (const float*)d_in[24];
  const float* bf2   = (const float*)d_in[25];
  const float* Wf3   = (const float*)d_in[26];
  const float* bf3   = (const float*)d_in[27];
  float* out = (float*)d_out;

  float* ws = (float*)d_ws;
  unsigned short* X2bf = (unsigned short*)ws;                // [B,XF] bf16
  float* Hb = (float*)(X2bf + (size_t)B * XF);               // [B,NH] f32
  float* TAP = Hb + (size_t)B * NH;                          // [C,12]
  unsigned short* FB1  = (unsigned short*)(TAP + (size_t)C * 12);
  unsigned short* FB2  = FB1 + (size_t)400 * 512;
  unsigned short* FQKV = FB2 + (size_t)200 * 512;
  unsigned short* FWo  = FQKV + (size_t)54 * 512;
  unsigned short* FWf1 = FWo + (size_t)18 * 512;             // 1950 x 512 bf16
  float* Yp = (float*)(FWf1 + (size_t)1950 * 512);           // [2B][SV]

  k_packW<<<669, 256, 0, stream>>>(W1, b1, Wd, bd, bn1_g, bn1_b, bn1_m, bn1_v, W2,
                                   Wq, Wk, Wv, Wo, Wf1, FB1, FB2, FQKV, FWo, FWf1, TAP);
  k_conv<<<2 * B, 512, 0, stream>>>(pep, mhc, FB1, FB2, TAP, Yp);
  k_attn<<<B, 256, 0, stream>>>(pep, mhc, Yp, b2, FQKV, FWo, ln_g, ln_b, X2bf);
  dim3 g5(16, 10);
  k_f1<<<g5, 256, 0, stream>>>(X2bf, FWf1, bf1, bn2_g, bn2_b, bn2_m, bn2_v, Hb);
  k_f23<<<B, 64, 0, stream>>>(Hb, Wf2, bf2, Wf3, bf3, out);
}